// Round 1
// baseline (1171.782 us; speedup 1.0000x reference)
//
#include <hip/hip_runtime.h>
#include <math.h>

#define N_NODES 50000
#define N_EDGES 800000
#define G_GRAPHS 64
#define HDIM 128
#define HID 32
#define NCLS 10
#define BN_EPS 1e-5f
#define SLOPE 0.2f

__device__ __forceinline__ float lrelu(float x) { return x > 0.f ? x : SLOPE * x; }

// ---------------- CSR build ----------------
__global__ void k_count_deg(const int* __restrict__ dst, int* __restrict__ deg) {
    int i = blockIdx.x * blockDim.x + threadIdx.x;
    if (i < N_EDGES) atomicAdd(&deg[dst[i]], 1);
}

// single block, 1024 threads: exclusive scan of deg -> row_ptr, cursor
__global__ __launch_bounds__(1024) void k_scan(const int* __restrict__ deg,
                                               int* __restrict__ row_ptr,
                                               int* __restrict__ cursor) {
    const int T = 1024;
    const int CH = (N_NODES + T - 1) / T;  // 49
    __shared__ int lds[T];
    int t = threadIdx.x;
    int base = t * CH;
    int s = 0;
    for (int k = 0; k < CH; ++k) {
        int i = base + k;
        if (i < N_NODES) s += deg[i];
    }
    lds[t] = s;
    __syncthreads();
    for (int off = 1; off < T; off <<= 1) {
        int v = (t >= off) ? lds[t - off] : 0;
        __syncthreads();
        lds[t] += v;
        __syncthreads();
    }
    int run = lds[t] - s;  // exclusive prefix of this thread's chunk
    for (int k = 0; k < CH; ++k) {
        int i = base + k;
        if (i < N_NODES) {
            row_ptr[i] = run;
            cursor[i] = run;
            run += deg[i];
        }
    }
    if (t == T - 1) row_ptr[N_NODES] = run;
}

__global__ void k_fill(const int* __restrict__ src, const int* __restrict__ dst,
                       int* __restrict__ cursor, int* __restrict__ ssrc) {
    int i = blockIdx.x * blockDim.x + threadIdx.x;
    if (i < N_EDGES) {
        int p = atomicAdd(&cursor[dst[i]], 1);
        ssrc[p] = src[i];
    }
}

__global__ void k_graph_bounds(const int* __restrict__ seg, int* __restrict__ gs) {
    int g = threadIdx.x;
    if (g > G_GRAPHS) return;
    int lo = 0, hi = N_NODES;
    while (lo < hi) {
        int mid = (lo + hi) >> 1;
        if (seg[mid] < g) lo = mid + 1; else hi = mid;
    }
    gs[g] = lo;
}

// ---------------- GEMM: H = X @ W + fb  (K = 128, cols = 128) ----------------
#define GB_ROWS 64
__global__ __launch_bounds__(256) void k_gemm(const float* __restrict__ X,
                                              const float* __restrict__ W,
                                              const float* __restrict__ fb,
                                              float* __restrict__ Hout) {
    __shared__ float xs[GB_ROWS][32];
    __shared__ float ws[32][HDIM];
    int t = threadIdx.x;
    int row0 = blockIdx.x * GB_ROWS;
    int tx = t & 31;   // col quad: cols tx*4..tx*4+3
    int ty = t >> 5;   // 0..7 -> rows ty*8..ty*8+7
    float acc[8][4] = {};
    for (int k0 = 0; k0 < HDIM; k0 += 32) {
        #pragma unroll
        for (int i = 0; i < 4; ++i) {
            int e4 = t + 256 * i;
            int kk = e4 >> 5;
            int c4 = e4 & 31;
            *(float4*)&ws[kk][c4 * 4] = *(const float4*)&W[(k0 + kk) * HDIM + c4 * 4];
        }
        #pragma unroll
        for (int i = 0; i < 2; ++i) {
            int e4 = t + 256 * i;
            int r = e4 >> 3;
            int k4 = e4 & 7;
            int gr = row0 + r;
            float4 v;
            if (gr < N_NODES) v = *(const float4*)&X[gr * HDIM + k0 + k4 * 4];
            else v = make_float4(0.f, 0.f, 0.f, 0.f);
            *(float4*)&xs[r][k4 * 4] = v;
        }
        __syncthreads();
        #pragma unroll
        for (int k = 0; k < 32; ++k) {
            float4 b = *(float4*)&ws[k][tx * 4];
            #pragma unroll
            for (int j = 0; j < 8; ++j) {
                float a = xs[ty * 8 + j][k];
                acc[j][0] = fmaf(a, b.x, acc[j][0]);
                acc[j][1] = fmaf(a, b.y, acc[j][1]);
                acc[j][2] = fmaf(a, b.z, acc[j][2]);
                acc[j][3] = fmaf(a, b.w, acc[j][3]);
            }
        }
        __syncthreads();
    }
    float4 bias = *(const float4*)&fb[tx * 4];
    #pragma unroll
    for (int j = 0; j < 8; ++j) {
        int gr = row0 + ty * 8 + j;
        if (gr < N_NODES) {
            float4 o = make_float4(acc[j][0] + bias.x, acc[j][1] + bias.y,
                                   acc[j][2] + bias.z, acc[j][3] + bias.w);
            *(float4*)&Hout[gr * HDIM + tx * 4] = o;
        }
    }
}

// ---------------- fused edge kernel: scores + online softmax + aggregate ----------------
__global__ __launch_bounds__(256) void k_edge(const float* __restrict__ H,
                                              const int* __restrict__ row_ptr,
                                              const int* __restrict__ ssrc,
                                              const float* __restrict__ attn,
                                              const float* __restrict__ ob,
                                              float* __restrict__ Y) {
    int wid = blockIdx.x * 4 + (threadIdx.x >> 6);
    int lane = threadIdx.x & 63;
    if (wid >= N_NODES) return;
    const int n = wid;
    float2 er = *(const float2*)&H[n * HDIM + lane * 2];
    float2 at = *(const float2*)&attn[lane * 2];
    float2 obv = *(const float2*)&ob[lane * 2];
    int beg = row_ptr[n], end = row_ptr[n + 1];
    float m = -INFINITY, den = 0.f, a0 = 0.f, a1 = 0.f;
    for (int j = beg; j < end; ++j) {
        int s = ssrc[j];
        float2 el = *(const float2*)&H[s * HDIM + lane * 2];
        float s0 = lrelu(el.x + er.x);
        float s1 = lrelu(el.y + er.y);
        float part = fmaf(s0, at.x, s1 * at.y);
        part += __shfl_xor(part, 1);
        part += __shfl_xor(part, 2);
        part += __shfl_xor(part, 4);
        part += __shfl_xor(part, 8);
        float e = part;                       // head score, uniform in 16-lane group
        float nm = fmaxf(m, e);
        float r = __expf(m - nm);             // exp(-inf)=0 on first edge
        float p = __expf(e - nm);
        den = fmaf(den, r, p);
        a0 = fmaf(a0, r, el.x * p);
        a1 = fmaf(a1, r, el.y * p);
        m = nm;
    }
    float inv = den > 0.f ? 1.f / den : 0.f;
    float o0 = fmaxf(fmaf(a0, inv, obv.x), 0.f);
    float o1 = fmaxf(fmaf(a1, inv, obv.y), 0.f);
    *(float2*)&Y[n * HDIM + lane * 2] = make_float2(o0, o1);
}

// ---------------- BatchNorm over nodes ----------------
__global__ __launch_bounds__(256) void k_bn_stats(const float* __restrict__ Y,
                                                  float* __restrict__ sums,
                                                  float* __restrict__ sumsq) {
    __shared__ float ls[256], lq[256];
    int t = threadIdx.x;
    int c = t & 127;
    int half = t >> 7;
    int r0 = blockIdx.x * 256;
    int rend = r0 + 256 < N_NODES ? r0 + 256 : N_NODES;
    float s = 0.f, q = 0.f;
    for (int r = r0 + half; r < rend; r += 2) {
        float v = Y[r * HDIM + c];
        s += v;
        q = fmaf(v, v, q);
    }
    ls[t] = s; lq[t] = q;
    __syncthreads();
    if (t < 128) {
        atomicAdd(&sums[c], ls[t] + ls[t + 128]);
        atomicAdd(&sumsq[c], lq[t] + lq[t + 128]);
    }
}

__global__ void k_bn_finalize(const float* __restrict__ sums, const float* __restrict__ sumsq,
                              const float* __restrict__ g, const float* __restrict__ b,
                              float* __restrict__ A, float* __restrict__ B) {
    int c = threadIdx.x;  // 128 threads
    float mu = sums[c] * (1.f / N_NODES);
    float var = fmaxf(sumsq[c] * (1.f / N_NODES) - mu * mu, 0.f);
    float inv = rsqrtf(var + BN_EPS);
    float a = g[c] * inv;
    A[c] = a;
    B[c] = b[c] - a * mu;
}

__global__ __launch_bounds__(256) void k_bn_apply(const float* __restrict__ Y,
                                                  const float* __restrict__ A,
                                                  const float* __restrict__ B,
                                                  float* __restrict__ X) {
    int i4 = blockIdx.x * blockDim.x + threadIdx.x;
    if (i4 >= N_NODES * HDIM / 4) return;
    int c4 = i4 & 31;
    float4 v = ((const float4*)Y)[i4];
    float4 a = *(const float4*)&A[c4 * 4];
    float4 bb = *(const float4*)&B[c4 * 4];
    float4 o = make_float4(fmaf(v.x, a.x, bb.x), fmaf(v.y, a.y, bb.y),
                           fmaf(v.z, a.z, bb.z), fmaf(v.w, a.w, bb.w));
    ((float4*)X)[i4] = o;
}

// ---------------- sum-pool per graph (seg sorted -> contiguous ranges) ----------------
__global__ __launch_bounds__(256) void k_pool(const float* __restrict__ X,
                                              const int* __restrict__ gs,
                                              float* __restrict__ pooled) {
    __shared__ float ls[256];
    int g = blockIdx.x;
    int t = threadIdx.x;
    int c = t & 127, half = t >> 7;
    int s = gs[g], e = gs[g + 1];
    float acc = 0.f;
    for (int r = s + half; r < e; r += 2) acc += X[r * HDIM + c];
    ls[t] = acc;
    __syncthreads();
    if (t < 128) pooled[g * HDIM + c] = ls[t] + ls[t + 128];
}

// ---------------- per-layer prediction head: relu(pooled@lw+lb) -> BN ----------------
__global__ __launch_bounds__(256) void k_pool_head(const float* __restrict__ pooled,
                                                   const float* __restrict__ lw,
                                                   const float* __restrict__ lb,
                                                   const float* __restrict__ lg,
                                                   const float* __restrict__ lbt,
                                                   float* __restrict__ pbn) {
    __shared__ float pl[G_GRAPHS][HID];
    __shared__ float sc[HID], sh[HID];
    int t = threadIdx.x;
    #pragma unroll
    for (int i = 0; i < (G_GRAPHS * HID) / 256; ++i) {  // 8
        int o = t + 256 * i;
        int row = o >> 5, col = o & 31;
        float acc = lb[col];
        for (int k = 0; k < HDIM; ++k) acc = fmaf(pooled[row * HDIM + k], lw[k * HID + col], acc);
        pl[row][col] = fmaxf(acc, 0.f);
    }
    __syncthreads();
    if (t < HID) {
        float s = 0.f, q = 0.f;
        for (int r = 0; r < G_GRAPHS; ++r) {
            float v = pl[r][t];
            s += v; q = fmaf(v, v, q);
        }
        float mu = s * (1.f / G_GRAPHS);
        float var = fmaxf(q * (1.f / G_GRAPHS) - mu * mu, 0.f);
        float inv = rsqrtf(var + BN_EPS);
        float a = lg[t] * inv;
        sc[t] = a;
        sh[t] = lbt[t] - a * mu;
    }
    __syncthreads();
    #pragma unroll
    for (int i = 0; i < 8; ++i) {
        int o = t + 256 * i;
        int row = o >> 5, col = o & 31;
        pbn[o] = fmaf(pl[row][col], sc[col], sh[col]);
    }
}

// ---------------- final MLP head + log_softmax ----------------
__global__ __launch_bounds__(256) void k_head(const float* __restrict__ pbn0,
                                              const float* __restrict__ pbn1,
                                              const float* __restrict__ pbn2,
                                              const float* __restrict__ mw1,
                                              const float* __restrict__ mg,
                                              const float* __restrict__ mb,
                                              const float* __restrict__ mw2,
                                              float* __restrict__ out) {
    __shared__ float hm[G_GRAPHS][HID];
    __shared__ float sc[HID], sh[HID];
    __shared__ float lgt[G_GRAPHS][NCLS];
    int t = threadIdx.x;
    const float* ph[3] = {pbn0, pbn1, pbn2};
    #pragma unroll
    for (int i = 0; i < 8; ++i) {
        int o = t + 256 * i;
        int row = o >> 5, col = o & 31;
        float acc = 0.f;
        for (int kb = 0; kb < 3; ++kb)
            for (int k = 0; k < HID; ++k)
                acc = fmaf(ph[kb][row * HID + k], mw1[(kb * HID + k) * HID + col], acc);
        hm[row][col] = acc;
    }
    __syncthreads();
    if (t < HID) {
        float s = 0.f, q = 0.f;
        for (int r = 0; r < G_GRAPHS; ++r) {
            float v = hm[r][t];
            s += v; q = fmaf(v, v, q);
        }
        float mu = s * (1.f / G_GRAPHS);
        float var = fmaxf(q * (1.f / G_GRAPHS) - mu * mu, 0.f);
        float inv = rsqrtf(var + BN_EPS);
        float a = mg[t] * inv;
        sc[t] = a;
        sh[t] = mb[t] - a * mu;
    }
    __syncthreads();
    #pragma unroll
    for (int i = 0; i < 8; ++i) {
        int o = t + 256 * i;
        int row = o >> 5, col = o & 31;
        hm[row][col] = fmaxf(fmaf(hm[row][col], sc[col], sh[col]), 0.f);
    }
    __syncthreads();
    #pragma unroll
    for (int i = 0; i < 3; ++i) {
        int o = t + 256 * i;
        if (o < G_GRAPHS * NCLS) {
            int row = o / NCLS, col = o % NCLS;
            float acc = 0.f;
            for (int k = 0; k < HID; ++k) acc = fmaf(hm[row][k], mw2[k * NCLS + col], acc);
            lgt[row][col] = acc;
        }
    }
    __syncthreads();
    if (t < G_GRAPHS) {
        float mx = -INFINITY;
        for (int c = 0; c < NCLS; ++c) mx = fmaxf(mx, lgt[t][c]);
        float s = 0.f;
        for (int c = 0; c < NCLS; ++c) s += expf(lgt[t][c] - mx);
        float lse = mx + logf(s);
        for (int c = 0; c < NCLS; ++c) out[t * NCLS + c] = lgt[t][c] - lse;
    }
}

extern "C" void kernel_launch(void* const* d_in, const int* in_sizes, int n_in,
                              void* d_out, int out_size, void* d_ws, size_t ws_size,
                              hipStream_t stream) {
    (void)in_sizes; (void)n_in; (void)out_size; (void)ws_size;
    const float* feat = (const float*)d_in[0];
    const int* src = (const int*)d_in[1];
    const int* dst = (const int*)d_in[2];
    const int* seg = (const int*)d_in[3];
    auto LP = [&](int l, int j) { return (const float*)d_in[4 + 10 * l + j]; };
    const float* mw1 = (const float*)d_in[34];
    const float* mg  = (const float*)d_in[35];
    const float* mb  = (const float*)d_in[36];
    const float* mw2 = (const float*)d_in[37];

    char* p = (char*)d_ws;
    auto alloc = [&](size_t bytes) { char* r = p; p += (bytes + 255) & ~(size_t)255; return r; };
    float* h      = (float*)alloc((size_t)N_NODES * HDIM * 4);
    float* y      = (float*)alloc((size_t)N_NODES * HDIM * 4);
    float* xbn    = (float*)alloc((size_t)N_NODES * HDIM * 4);
    int*   ssrc   = (int*)alloc((size_t)N_EDGES * 4);
    int*   rp     = (int*)alloc((size_t)(N_NODES + 1) * 4);
    int*   cursor = (int*)alloc((size_t)N_NODES * 4);
    int*   deg    = (int*)alloc((size_t)N_NODES * 4);
    float* stats  = (float*)alloc(256 * 4);           // sums[128] | sumsq[128]
    float* sums   = stats;
    float* sumsq  = stats + 128;
    float* Abuf   = (float*)alloc(128 * 4);
    float* Bbuf   = (float*)alloc(128 * 4);
    float* pooled = (float*)alloc((size_t)G_GRAPHS * HDIM * 4);
    float* pbn    = (float*)alloc((size_t)3 * G_GRAPHS * HID * 4);
    int*   gs     = (int*)alloc((size_t)(G_GRAPHS + 1) * 4);

    // CSR build (deterministic per call)
    hipMemsetAsync(deg, 0, (size_t)N_NODES * 4, stream);
    k_count_deg<<<(N_EDGES + 255) / 256, 256, 0, stream>>>(dst, deg);
    k_scan<<<1, 1024, 0, stream>>>(deg, rp, cursor);
    k_fill<<<(N_EDGES + 255) / 256, 256, 0, stream>>>(src, dst, cursor, ssrc);
    k_graph_bounds<<<1, 128, 0, stream>>>(seg, gs);

    const float* x = feat;
    for (int l = 0; l < 3; ++l) {
        k_gemm<<<(N_NODES + GB_ROWS - 1) / GB_ROWS, 256, 0, stream>>>(x, LP(l, 0), LP(l, 1), h);
        k_edge<<<(N_NODES + 3) / 4, 256, 0, stream>>>(h, rp, ssrc, LP(l, 2), LP(l, 3), y);
        hipMemsetAsync(stats, 0, 256 * 4, stream);
        k_bn_stats<<<(N_NODES + 255) / 256, 256, 0, stream>>>(y, sums, sumsq);
        k_bn_finalize<<<1, 128, 0, stream>>>(sums, sumsq, LP(l, 4), LP(l, 5), Abuf, Bbuf);
        k_bn_apply<<<(N_NODES * HDIM / 4 + 255) / 256, 256, 0, stream>>>(y, Abuf, Bbuf, xbn);
        k_pool<<<G_GRAPHS, 256, 0, stream>>>(xbn, gs, pooled);
        k_pool_head<<<1, 256, 0, stream>>>(pooled, LP(l, 6), LP(l, 7), LP(l, 8), LP(l, 9),
                                           pbn + (size_t)l * G_GRAPHS * HID);
        x = xbn;
    }
    k_head<<<1, 256, 0, stream>>>(pbn, pbn + G_GRAPHS * HID, pbn + 2 * G_GRAPHS * HID,
                                  mw1, mg, mb, mw2, (float*)d_out);
}

// Round 2
// 752.254 us; speedup vs baseline: 1.5577x; 1.5577x over previous
//
#include <hip/hip_runtime.h>
#include <math.h>

#define N_NODES 50000
#define N_EDGES 800000
#define G_GRAPHS 64
#define HDIM 128
#define HID 32
#define NCLS 10
#define BN_EPS 1e-5f
#define SLOPE 0.2f
#define NB_SCAN 196  // ceil(N_NODES/256)

__device__ __forceinline__ float lrelu(float x) { return x > 0.f ? x : SLOPE * x; }

// ---------------- CSR build ----------------
__global__ void k_count_deg(const int* __restrict__ dst, int* __restrict__ deg) {
    int i = blockIdx.x * blockDim.x + threadIdx.x;
    if (i < N_EDGES) atomicAdd(&deg[dst[i]], 1);
}

__global__ __launch_bounds__(256) void k_blocksum(const int* __restrict__ deg,
                                                  int* __restrict__ bsum) {
    __shared__ int ls[256];
    int t = threadIdx.x;
    int i = blockIdx.x * 256 + t;
    int v = i < N_NODES ? deg[i] : 0;
    ls[t] = v;
    __syncthreads();
    for (int off = 128; off > 0; off >>= 1) {
        if (t < off) ls[t] += ls[t + off];
        __syncthreads();
    }
    if (t == 0) bsum[blockIdx.x] = ls[0];
}

__global__ __launch_bounds__(256) void k_scan_bsums(const int* __restrict__ bsum,
                                                    int* __restrict__ boff) {
    __shared__ int ls[256];
    int t = threadIdx.x;
    int v = t < NB_SCAN ? bsum[t] : 0;
    ls[t] = v;
    __syncthreads();
    for (int off = 1; off < 256; off <<= 1) {
        int u = t >= off ? ls[t - off] : 0;
        __syncthreads();
        ls[t] += u;
        __syncthreads();
    }
    if (t < NB_SCAN) boff[t] = ls[t] - v;  // exclusive
}

__global__ __launch_bounds__(256) void k_rowptr(const int* __restrict__ deg,
                                                const int* __restrict__ boff,
                                                int* __restrict__ row_ptr,
                                                int* __restrict__ cursor) {
    __shared__ int ls[256];
    int t = threadIdx.x;
    int i = blockIdx.x * 256 + t;
    int v = i < N_NODES ? deg[i] : 0;
    ls[t] = v;
    __syncthreads();
    for (int off = 1; off < 256; off <<= 1) {
        int u = t >= off ? ls[t - off] : 0;
        __syncthreads();
        ls[t] += u;
        __syncthreads();
    }
    int excl = ls[t] - v + boff[blockIdx.x];
    if (i < N_NODES) {
        row_ptr[i] = excl;
        cursor[i] = excl;
    }
    if (i == N_NODES - 1) row_ptr[N_NODES] = excl + v;
}

__global__ void k_fill(const int* __restrict__ src, const int* __restrict__ dst,
                       int* __restrict__ cursor, int* __restrict__ ssrc) {
    int i = blockIdx.x * blockDim.x + threadIdx.x;
    if (i < N_EDGES) {
        int p = atomicAdd(&cursor[dst[i]], 1);
        ssrc[p] = src[i];
    }
}

__global__ void k_graph_bounds(const int* __restrict__ seg, int* __restrict__ gs) {
    int g = threadIdx.x;
    if (g > G_GRAPHS) return;
    int lo = 0, hi = N_NODES;
    while (lo < hi) {
        int mid = (lo + hi) >> 1;
        if (seg[mid] < g) lo = mid + 1; else hi = mid;
    }
    gs[g] = lo;
}

// ---------------- GEMM: H = affine(X) @ W + fb  (K = 128, cols = 128) ----------------
// affine(X)[r][k] = A[k]*X[r][k] + B[k] when useAffine (folds previous layer's BN)
#define GB_ROWS 64
__global__ __launch_bounds__(256) void k_gemm(const float* __restrict__ X,
                                              const float* __restrict__ W,
                                              const float* __restrict__ fb,
                                              const float* __restrict__ Aff,
                                              const float* __restrict__ Bff,
                                              int useAffine,
                                              float* __restrict__ Hout) {
    __shared__ float xs[GB_ROWS][32];
    __shared__ float ws[32][HDIM];
    int t = threadIdx.x;
    int row0 = blockIdx.x * GB_ROWS;
    int tx = t & 31;   // col quad: cols tx*4..tx*4+3
    int ty = t >> 5;   // 0..7 -> rows ty*8..ty*8+7
    float acc[8][4] = {};
    for (int k0 = 0; k0 < HDIM; k0 += 32) {
        #pragma unroll
        for (int i = 0; i < 4; ++i) {
            int e4 = t + 256 * i;
            int kk = e4 >> 5;
            int c4 = e4 & 31;
            *(float4*)&ws[kk][c4 * 4] = *(const float4*)&W[(k0 + kk) * HDIM + c4 * 4];
        }
        #pragma unroll
        for (int i = 0; i < 2; ++i) {
            int e4 = t + 256 * i;
            int r = e4 >> 3;
            int k4 = e4 & 7;
            int gr = row0 + r;
            float4 v;
            if (gr < N_NODES) v = *(const float4*)&X[gr * HDIM + k0 + k4 * 4];
            else v = make_float4(0.f, 0.f, 0.f, 0.f);
            if (useAffine) {
                float4 av = *(const float4*)&Aff[k0 + k4 * 4];
                float4 bv = *(const float4*)&Bff[k0 + k4 * 4];
                v.x = fmaf(v.x, av.x, bv.x);
                v.y = fmaf(v.y, av.y, bv.y);
                v.z = fmaf(v.z, av.z, bv.z);
                v.w = fmaf(v.w, av.w, bv.w);
            }
            *(float4*)&xs[r][k4 * 4] = v;
        }
        __syncthreads();
        #pragma unroll
        for (int k = 0; k < 32; ++k) {
            float4 b = *(float4*)&ws[k][tx * 4];
            #pragma unroll
            for (int j = 0; j < 8; ++j) {
                float a = xs[ty * 8 + j][k];
                acc[j][0] = fmaf(a, b.x, acc[j][0]);
                acc[j][1] = fmaf(a, b.y, acc[j][1]);
                acc[j][2] = fmaf(a, b.z, acc[j][2]);
                acc[j][3] = fmaf(a, b.w, acc[j][3]);
            }
        }
        __syncthreads();
    }
    float4 bias = *(const float4*)&fb[tx * 4];
    #pragma unroll
    for (int j = 0; j < 8; ++j) {
        int gr = row0 + ty * 8 + j;
        if (gr < N_NODES) {
            float4 o = make_float4(acc[j][0] + bias.x, acc[j][1] + bias.y,
                                   acc[j][2] + bias.z, acc[j][3] + bias.w);
            *(float4*)&Hout[gr * HDIM + tx * 4] = o;
        }
    }
}

// ---------------- fused edge kernel: scores + online softmax + aggregate ----------------
__global__ __launch_bounds__(256) void k_edge(const float* __restrict__ H,
                                              const int* __restrict__ row_ptr,
                                              const int* __restrict__ ssrc,
                                              const float* __restrict__ attn,
                                              const float* __restrict__ ob,
                                              float* __restrict__ Y) {
    int wid = blockIdx.x * 4 + (threadIdx.x >> 6);
    int lane = threadIdx.x & 63;
    if (wid >= N_NODES) return;
    const int n = wid;
    float2 er = *(const float2*)&H[n * HDIM + lane * 2];
    float2 at = *(const float2*)&attn[lane * 2];
    float2 obv = *(const float2*)&ob[lane * 2];
    int beg = row_ptr[n], end = row_ptr[n + 1];
    float m = -INFINITY, den = 0.f, a0 = 0.f, a1 = 0.f;
    float2 nxt;
    if (beg < end) {
        int s0 = ssrc[beg];
        nxt = *(const float2*)&H[s0 * HDIM + lane * 2];
    }
    for (int j = beg; j < end; ++j) {
        float2 el = nxt;
        int jn = j + 1;
        if (jn < end) {
            int s = ssrc[jn];
            nxt = *(const float2*)&H[s * HDIM + lane * 2];  // in flight during compute
        }
        float s0 = lrelu(el.x + er.x);
        float s1 = lrelu(el.y + er.y);
        float part = fmaf(s0, at.x, s1 * at.y);
        part += __shfl_xor(part, 1);
        part += __shfl_xor(part, 2);
        part += __shfl_xor(part, 4);
        part += __shfl_xor(part, 8);
        float e = part;                       // head score, uniform in 16-lane group
        float nm = fmaxf(m, e);
        float r = __expf(m - nm);             // exp(-inf)=0 on first edge
        float p = __expf(e - nm);
        den = fmaf(den, r, p);
        a0 = fmaf(a0, r, el.x * p);
        a1 = fmaf(a1, r, el.y * p);
        m = nm;
    }
    float inv = den > 0.f ? 1.f / den : 0.f;
    float o0 = fmaxf(fmaf(a0, inv, obv.x), 0.f);
    float o1 = fmaxf(fmaf(a1, inv, obv.y), 0.f);
    *(float2*)&Y[n * HDIM + lane * 2] = make_float2(o0, o1);
}

// ---------------- fused BN stats + per-graph sum pool (single pass over Y) ----------------
__global__ __launch_bounds__(256) void k_stats_pool(const float* __restrict__ Y,
                                                    const int* __restrict__ seg,
                                                    float* __restrict__ sums,
                                                    float* __restrict__ sumsq,
                                                    float* __restrict__ pooled) {
    __shared__ float ls[256], lq[256];
    __shared__ int sseg[256];
    int t = threadIdx.x;
    int r0 = blockIdx.x * 256;
    if (r0 + t < N_NODES) sseg[t] = seg[r0 + t];
    __syncthreads();
    int c = t & 127, half = t >> 7;
    int rend = r0 + 256 < N_NODES ? r0 + 256 : N_NODES;
    float s = 0.f, q = 0.f;
    int curg = -1;
    float run = 0.f;
    for (int r = r0 + half; r < rend; r += 2) {
        float v = Y[r * HDIM + c];
        s += v;
        q = fmaf(v, v, q);
        int g = sseg[r - r0];
        if (g != curg) {
            if (curg >= 0) atomicAdd(&pooled[curg * HDIM + c], run);
            curg = g;
            run = v;
        } else {
            run += v;
        }
    }
    if (curg >= 0) atomicAdd(&pooled[curg * HDIM + c], run);
    ls[t] = s; lq[t] = q;
    __syncthreads();
    if (t < 128) {
        atomicAdd(&sums[c], ls[t] + ls[t + 128]);
        atomicAdd(&sumsq[c], lq[t] + lq[t + 128]);
    }
}

__global__ void k_bn_finalize(const float* __restrict__ sums, const float* __restrict__ sumsq,
                              const float* __restrict__ g, const float* __restrict__ b,
                              float* __restrict__ A, float* __restrict__ B) {
    int c = threadIdx.x;  // 128 threads
    float mu = sums[c] * (1.f / N_NODES);
    float var = fmaxf(sumsq[c] * (1.f / N_NODES) - mu * mu, 0.f);
    float inv = rsqrtf(var + BN_EPS);
    float a = g[c] * inv;
    A[c] = a;
    B[c] = b[c] - a * mu;
}

// ---------------- per-layer prediction head ----------------
// input: pooled_y (pre-BN). pooled_bn[g][k] = A[k]*pooled_y[g][k] + cnt_g*B[k]
__global__ __launch_bounds__(256) void k_pool_head(const float* __restrict__ pooled,
                                                   const float* __restrict__ A,
                                                   const float* __restrict__ B,
                                                   const int* __restrict__ gs,
                                                   const float* __restrict__ lw,
                                                   const float* __restrict__ lb,
                                                   const float* __restrict__ lg,
                                                   const float* __restrict__ lbt,
                                                   float* __restrict__ pbn) {
    __shared__ float pl[G_GRAPHS][HID];
    __shared__ float sc[HID], sh[HID];
    int t = threadIdx.x;
    #pragma unroll
    for (int i = 0; i < (G_GRAPHS * HID) / 256; ++i) {  // 8
        int o = t + 256 * i;
        int row = o >> 5, col = o & 31;
        float cnt = (float)(gs[row + 1] - gs[row]);
        float acc = lb[col];
        for (int k = 0; k < HDIM; ++k) {
            float pin = fmaf(A[k], pooled[row * HDIM + k], cnt * B[k]);
            acc = fmaf(pin, lw[k * HID + col], acc);
        }
        pl[row][col] = fmaxf(acc, 0.f);
    }
    __syncthreads();
    if (t < HID) {
        float s = 0.f, q = 0.f;
        for (int r = 0; r < G_GRAPHS; ++r) {
            float v = pl[r][t];
            s += v; q = fmaf(v, v, q);
        }
        float mu = s * (1.f / G_GRAPHS);
        float var = fmaxf(q * (1.f / G_GRAPHS) - mu * mu, 0.f);
        float inv = rsqrtf(var + BN_EPS);
        float a = lg[t] * inv;
        sc[t] = a;
        sh[t] = lbt[t] - a * mu;
    }
    __syncthreads();
    #pragma unroll
    for (int i = 0; i < 8; ++i) {
        int o = t + 256 * i;
        int row = o >> 5, col = o & 31;
        pbn[o] = fmaf(pl[row][col], sc[col], sh[col]);
    }
}

// ---------------- final MLP head + log_softmax ----------------
__global__ __launch_bounds__(256) void k_head(const float* __restrict__ pbn0,
                                              const float* __restrict__ pbn1,
                                              const float* __restrict__ pbn2,
                                              const float* __restrict__ mw1,
                                              const float* __restrict__ mg,
                                              const float* __restrict__ mb,
                                              const float* __restrict__ mw2,
                                              float* __restrict__ out) {
    __shared__ float hm[G_GRAPHS][HID];
    __shared__ float sc[HID], sh[HID];
    __shared__ float lgt[G_GRAPHS][NCLS];
    int t = threadIdx.x;
    const float* ph[3] = {pbn0, pbn1, pbn2};
    #pragma unroll
    for (int i = 0; i < 8; ++i) {
        int o = t + 256 * i;
        int row = o >> 5, col = o & 31;
        float acc = 0.f;
        for (int kb = 0; kb < 3; ++kb)
            for (int k = 0; k < HID; ++k)
                acc = fmaf(ph[kb][row * HID + k], mw1[(kb * HID + k) * HID + col], acc);
        hm[row][col] = acc;
    }
    __syncthreads();
    if (t < HID) {
        float s = 0.f, q = 0.f;
        for (int r = 0; r < G_GRAPHS; ++r) {
            float v = hm[r][t];
            s += v; q = fmaf(v, v, q);
        }
        float mu = s * (1.f / G_GRAPHS);
        float var = fmaxf(q * (1.f / G_GRAPHS) - mu * mu, 0.f);
        float inv = rsqrtf(var + BN_EPS);
        float a = mg[t] * inv;
        sc[t] = a;
        sh[t] = mb[t] - a * mu;
    }
    __syncthreads();
    #pragma unroll
    for (int i = 0; i < 8; ++i) {
        int o = t + 256 * i;
        int row = o >> 5, col = o & 31;
        hm[row][col] = fmaxf(fmaf(hm[row][col], sc[col], sh[col]), 0.f);
    }
    __syncthreads();
    #pragma unroll
    for (int i = 0; i < 3; ++i) {
        int o = t + 256 * i;
        if (o < G_GRAPHS * NCLS) {
            int row = o / NCLS, col = o % NCLS;
            float acc = 0.f;
            for (int k = 0; k < HID; ++k) acc = fmaf(hm[row][k], mw2[k * NCLS + col], acc);
            lgt[row][col] = acc;
        }
    }
    __syncthreads();
    if (t < G_GRAPHS) {
        float mx = -INFINITY;
        for (int c = 0; c < NCLS; ++c) mx = fmaxf(mx, lgt[t][c]);
        float s = 0.f;
        for (int c = 0; c < NCLS; ++c) s += expf(lgt[t][c] - mx);
        float lse = mx + logf(s);
        for (int c = 0; c < NCLS; ++c) out[t * NCLS + c] = lgt[t][c] - lse;
    }
}

extern "C" void kernel_launch(void* const* d_in, const int* in_sizes, int n_in,
                              void* d_out, int out_size, void* d_ws, size_t ws_size,
                              hipStream_t stream) {
    (void)in_sizes; (void)n_in; (void)out_size; (void)ws_size;
    const float* feat = (const float*)d_in[0];
    const int* src = (const int*)d_in[1];
    const int* dst = (const int*)d_in[2];
    const int* seg = (const int*)d_in[3];
    auto LP = [&](int l, int j) { return (const float*)d_in[4 + 10 * l + j]; };
    const float* mw1 = (const float*)d_in[34];
    const float* mg  = (const float*)d_in[35];
    const float* mb  = (const float*)d_in[36];
    const float* mw2 = (const float*)d_in[37];

    char* p = (char*)d_ws;
    auto alloc = [&](size_t bytes) { char* r = p; p += (bytes + 255) & ~(size_t)255; return r; };
    float* h      = (float*)alloc((size_t)N_NODES * HDIM * 4);
    float* y      = (float*)alloc((size_t)N_NODES * HDIM * 4);
    int*   ssrc   = (int*)alloc((size_t)N_EDGES * 4);
    int*   rp     = (int*)alloc((size_t)(N_NODES + 1) * 4);
    int*   cursor = (int*)alloc((size_t)N_NODES * 4);
    int*   deg    = (int*)alloc((size_t)N_NODES * 4);
    float* stats  = (float*)alloc((size_t)(256 + G_GRAPHS * HDIM) * 4);  // sums|sumsq|pooled
    float* sums   = stats;
    float* sumsq  = stats + 128;
    float* pooled = stats + 256;
    float* Abuf   = (float*)alloc(128 * 4);
    float* Bbuf   = (float*)alloc(128 * 4);
    float* pbn    = (float*)alloc((size_t)3 * G_GRAPHS * HID * 4);
    int*   gs     = (int*)alloc((size_t)(G_GRAPHS + 1) * 4);
    int*   bsum   = (int*)alloc((size_t)NB_SCAN * 4);
    int*   boff   = (int*)alloc((size_t)NB_SCAN * 4);

    // CSR build (deterministic per call)
    hipMemsetAsync(deg, 0, (size_t)N_NODES * 4, stream);
    k_count_deg<<<(N_EDGES + 255) / 256, 256, 0, stream>>>(dst, deg);
    k_blocksum<<<NB_SCAN, 256, 0, stream>>>(deg, bsum);
    k_scan_bsums<<<1, 256, 0, stream>>>(bsum, boff);
    k_rowptr<<<NB_SCAN, 256, 0, stream>>>(deg, boff, rp, cursor);
    k_fill<<<(N_EDGES + 255) / 256, 256, 0, stream>>>(src, dst, cursor, ssrc);
    k_graph_bounds<<<1, 128, 0, stream>>>(seg, gs);

    const float* x = feat;
    for (int l = 0; l < 3; ++l) {
        k_gemm<<<(N_NODES + GB_ROWS - 1) / GB_ROWS, 256, 0, stream>>>(
            x, LP(l, 0), LP(l, 1), Abuf, Bbuf, l > 0 ? 1 : 0, h);
        k_edge<<<(N_NODES + 3) / 4, 256, 0, stream>>>(h, rp, ssrc, LP(l, 2), LP(l, 3), y);
        hipMemsetAsync(stats, 0, (size_t)(256 + G_GRAPHS * HDIM) * 4, stream);
        k_stats_pool<<<NB_SCAN, 256, 0, stream>>>(y, seg, sums, sumsq, pooled);
        k_bn_finalize<<<1, 128, 0, stream>>>(sums, sumsq, LP(l, 4), LP(l, 5), Abuf, Bbuf);
        k_pool_head<<<1, 256, 0, stream>>>(pooled, Abuf, Bbuf, gs, LP(l, 6), LP(l, 7),
                                           LP(l, 8), LP(l, 9),
                                           pbn + (size_t)l * G_GRAPHS * HID);
        x = y;  // next layer folds BN(y) via Abuf/Bbuf inside k_gemm
    }
    k_head<<<1, 256, 0, stream>>>(pbn, pbn + G_GRAPHS * HID, pbn + 2 * G_GRAPHS * HID,
                                  mw1, mg, mb, mw2, (float*)d_out);
}

// Round 3
// 547.155 us; speedup vs baseline: 2.1416x; 1.3748x over previous
//
#include <hip/hip_runtime.h>
#include <math.h>

#define N_NODES 50000
#define N_EDGES 800000
#define G_GRAPHS 64
#define HDIM 128
#define HID 32
#define NCLS 10
#define BN_EPS 1e-5f
#define SLOPE 0.2f
#define NB_SCAN 196  // ceil(N_NODES/256)
#define STATS_STRIDE (256 + G_GRAPHS * HDIM)

typedef __attribute__((ext_vector_type(8))) short bf16x8;
typedef __attribute__((ext_vector_type(4))) float f32x4;

__device__ __forceinline__ float lrelu(float x) { return x > 0.f ? x : SLOPE * x; }

__device__ __forceinline__ unsigned short f2bf(float x) {
    unsigned int u = __float_as_uint(x);
    u = (u + 0x7fffu + ((u >> 16) & 1u)) >> 16;
    return (unsigned short)u;
}
__device__ __forceinline__ float2 up2(unsigned int u) {
    return make_float2(__uint_as_float(u << 16), __uint_as_float(u & 0xffff0000u));
}

// ---------------- CSR build ----------------
__global__ void k_count_deg(const int* __restrict__ dst, int* __restrict__ deg) {
    int i = blockIdx.x * blockDim.x + threadIdx.x;
    if (i < N_EDGES) atomicAdd(&deg[dst[i]], 1);
}

__global__ __launch_bounds__(256) void k_blocksum(const int* __restrict__ deg,
                                                  int* __restrict__ bsum) {
    __shared__ int ls[256];
    int t = threadIdx.x;
    int i = blockIdx.x * 256 + t;
    int v = i < N_NODES ? deg[i] : 0;
    ls[t] = v;
    __syncthreads();
    for (int off = 128; off > 0; off >>= 1) {
        if (t < off) ls[t] += ls[t + off];
        __syncthreads();
    }
    if (t == 0) bsum[blockIdx.x] = ls[0];
}

__global__ __launch_bounds__(256) void k_scan_bsums(const int* __restrict__ bsum,
                                                    int* __restrict__ boff) {
    __shared__ int ls[256];
    int t = threadIdx.x;
    int v = t < NB_SCAN ? bsum[t] : 0;
    ls[t] = v;
    __syncthreads();
    for (int off = 1; off < 256; off <<= 1) {
        int u = t >= off ? ls[t - off] : 0;
        __syncthreads();
        ls[t] += u;
        __syncthreads();
    }
    if (t < NB_SCAN) boff[t] = ls[t] - v;  // exclusive
}

__global__ __launch_bounds__(256) void k_rowptr(const int* __restrict__ deg,
                                                const int* __restrict__ boff,
                                                int* __restrict__ row_ptr,
                                                int* __restrict__ cursor) {
    __shared__ int ls[256];
    int t = threadIdx.x;
    int i = blockIdx.x * 256 + t;
    int v = i < N_NODES ? deg[i] : 0;
    ls[t] = v;
    __syncthreads();
    for (int off = 1; off < 256; off <<= 1) {
        int u = t >= off ? ls[t - off] : 0;
        __syncthreads();
        ls[t] += u;
        __syncthreads();
    }
    int excl = ls[t] - v + boff[blockIdx.x];
    if (i < N_NODES) {
        row_ptr[i] = excl;
        cursor[i] = excl;
    }
    if (i == N_NODES - 1) row_ptr[N_NODES] = excl + v;
}

__global__ void k_fill(const int* __restrict__ src, const int* __restrict__ dst,
                       int* __restrict__ cursor, int* __restrict__ ssrc) {
    int i = blockIdx.x * blockDim.x + threadIdx.x;
    if (i < N_EDGES) {
        int p = atomicAdd(&cursor[dst[i]], 1);
        ssrc[p] = src[i];
    }
}

__global__ void k_graph_bounds(const int* __restrict__ seg, int* __restrict__ gs) {
    int g = threadIdx.x;
    if (g > G_GRAPHS) return;
    int lo = 0, hi = N_NODES;
    while (lo < hi) {
        int mid = (lo + hi) >> 1;
        if (seg[mid] < g) lo = mid + 1; else hi = mid;
    }
    gs[g] = lo;
}

// ---------------- W -> MFMA B-fragment layout (bf16), once per layer ----------------
// B-frag for 16x16x32: lane = kg*16 + j holds W[ks*32 + kg*8 + e][cs*16 + j], e=0..7
// WL[((ks*8+cs)*64 + lane)*8 + e]
__global__ __launch_bounds__(256) void k_prep_w(const float* __restrict__ W,
                                                unsigned short* __restrict__ WL) {
    for (int idx = blockIdx.x * 256 + threadIdx.x; idx < HDIM * HDIM; idx += 16 * 256) {
        int k = idx >> 7, c = idx & 127;
        int ks = k >> 5, kg = (k >> 3) & 3, e = k & 7;
        int cs = c >> 4, jj = c & 15;
        int lane = kg * 16 + jj;
        WL[(((ks << 3) + cs) * 64 + lane) * 8 + e] = f2bf(W[idx]);
    }
}

// ---------------- MFMA GEMM: Hb = bf16( affine(X) @ W + fb ), no LDS ----------------
__global__ __launch_bounds__(256) void k_gemm_mfma(const float* __restrict__ X,
                                                   const unsigned short* __restrict__ WL,
                                                   const float* __restrict__ fb,
                                                   const float* __restrict__ Aff,
                                                   const float* __restrict__ Bff,
                                                   int useAffine,
                                                   unsigned short* __restrict__ Hb) {
    int t = threadIdx.x;
    int w = t >> 6, lane = t & 63;
    int i16 = lane & 15, kg = lane >> 4;
    int r0w = blockIdx.x * 64 + w * 16;
    int row = r0w + i16;
    int rowc = row < N_NODES ? row : N_NODES - 1;

    f32x4 acc[8];
    #pragma unroll
    for (int cs = 0; cs < 8; ++cs) acc[cs] = (f32x4){0.f, 0.f, 0.f, 0.f};

    #pragma unroll
    for (int ks = 0; ks < 4; ++ks) {
        const float* xp = X + (size_t)rowc * HDIM + ks * 32 + kg * 8;
        float4 v0 = *(const float4*)xp;
        float4 v1 = *(const float4*)(xp + 4);
        if (useAffine) {
            const float* ap = Aff + ks * 32 + kg * 8;
            const float* bp = Bff + ks * 32 + kg * 8;
            float4 a0 = *(const float4*)ap, a1 = *(const float4*)(ap + 4);
            float4 b0 = *(const float4*)bp, b1 = *(const float4*)(bp + 4);
            v0.x = fmaf(v0.x, a0.x, b0.x); v0.y = fmaf(v0.y, a0.y, b0.y);
            v0.z = fmaf(v0.z, a0.z, b0.z); v0.w = fmaf(v0.w, a0.w, b0.w);
            v1.x = fmaf(v1.x, a1.x, b1.x); v1.y = fmaf(v1.y, a1.y, b1.y);
            v1.z = fmaf(v1.z, a1.z, b1.z); v1.w = fmaf(v1.w, a1.w, b1.w);
        }
        union { uint4 u; bf16x8 s; } af;
        af.u.x = (unsigned int)f2bf(v0.x) | ((unsigned int)f2bf(v0.y) << 16);
        af.u.y = (unsigned int)f2bf(v0.z) | ((unsigned int)f2bf(v0.w) << 16);
        af.u.z = (unsigned int)f2bf(v1.x) | ((unsigned int)f2bf(v1.y) << 16);
        af.u.w = (unsigned int)f2bf(v1.z) | ((unsigned int)f2bf(v1.w) << 16);
        #pragma unroll
        for (int cs = 0; cs < 8; ++cs) {
            union { uint4 u; bf16x8 s; } bw;
            bw.u = *(const uint4*)&WL[(((ks << 3) + cs) * 64 + lane) * 8];
            acc[cs] = __builtin_amdgcn_mfma_f32_16x16x32_bf16(af.s, bw.s, acc[cs], 0, 0, 0);
        }
    }

    // D: col = cs*16 + (lane&15), row = r0w + (lane>>4)*4 + p
    #pragma unroll
    for (int cs = 0; cs < 8; ++cs) {
        int col = cs * 16 + i16;
        float bias = fb[col];
        #pragma unroll
        for (int p = 0; p < 4; ++p) {
            int r = r0w + kg * 4 + p;
            if (r < N_NODES) Hb[(size_t)r * HDIM + col] = f2bf(acc[cs][p] + bias);
        }
    }
}

// ---------------- fused edge kernel (bf16 gathers, 2-edge unrolled online softmax) ----------------
__global__ __launch_bounds__(256) void k_edge(const unsigned short* __restrict__ Hb,
                                              const int* __restrict__ row_ptr,
                                              const int* __restrict__ ssrc,
                                              const float* __restrict__ attn,
                                              const float* __restrict__ ob,
                                              float* __restrict__ Y) {
    int wid = blockIdx.x * 4 + (threadIdx.x >> 6);
    int lane = threadIdx.x & 63;
    if (wid >= N_NODES) return;
    const int n = wid;
    float2 er = up2(*(const unsigned int*)&Hb[(size_t)n * HDIM + (lane << 1)]);
    float2 at = *(const float2*)&attn[lane << 1];
    float2 obv = *(const float2*)&ob[lane << 1];
    int beg = row_ptr[n], end = row_ptr[n + 1];

    float m = -INFINITY, den = 0.f, a0 = 0.f, a1 = 0.f;

    unsigned int u0 = 0, u1 = 0;
    int j = beg;
    if (j + 1 < end) {
        int s0 = ssrc[j], s1 = ssrc[j + 1];
        u0 = *(const unsigned int*)&Hb[(size_t)s0 * HDIM + (lane << 1)];
        u1 = *(const unsigned int*)&Hb[(size_t)s1 * HDIM + (lane << 1)];
    }
    while (j + 1 < end) {
        int jn = j + 2;
        unsigned int w0 = u0, w1 = u1;
        if (jn + 1 < end) {
            int t0 = ssrc[jn], t1 = ssrc[jn + 1];
            u0 = *(const unsigned int*)&Hb[(size_t)t0 * HDIM + (lane << 1)];
            u1 = *(const unsigned int*)&Hb[(size_t)t1 * HDIM + (lane << 1)];
        }
        float2 el0 = up2(w0), el1 = up2(w1);
        float p0 = fmaf(lrelu(el0.x + er.x), at.x, lrelu(el0.y + er.y) * at.y);
        float p1 = fmaf(lrelu(el1.x + er.x), at.x, lrelu(el1.y + er.y) * at.y);
        p0 += __shfl_xor(p0, 1); p1 += __shfl_xor(p1, 1);
        p0 += __shfl_xor(p0, 2); p1 += __shfl_xor(p1, 2);
        p0 += __shfl_xor(p0, 4); p1 += __shfl_xor(p1, 4);
        p0 += __shfl_xor(p0, 8); p1 += __shfl_xor(p1, 8);
        float nm = fmaxf(m, fmaxf(p0, p1));
        float r = __expf(m - nm);
        float q0 = __expf(p0 - nm), q1 = __expf(p1 - nm);
        den = fmaf(den, r, q0 + q1);
        a0 = fmaf(a0, r, fmaf(el0.x, q0, el1.x * q1));
        a1 = fmaf(a1, r, fmaf(el0.y, q0, el1.y * q1));
        m = nm;
        j = jn;
    }
    if (j < end) {  // tail (also the deg==1 case)
        int s = ssrc[j];
        float2 el = up2(*(const unsigned int*)&Hb[(size_t)s * HDIM + (lane << 1)]);
        float p = fmaf(lrelu(el.x + er.x), at.x, lrelu(el.y + er.y) * at.y);
        p += __shfl_xor(p, 1);
        p += __shfl_xor(p, 2);
        p += __shfl_xor(p, 4);
        p += __shfl_xor(p, 8);
        float nm = fmaxf(m, p);
        float r = __expf(m - nm);
        float q = __expf(p - nm);
        den = fmaf(den, r, q);
        a0 = fmaf(a0, r, el.x * q);
        a1 = fmaf(a1, r, el.y * q);
    }
    float inv = den > 0.f ? 1.f / den : 0.f;
    float o0 = fmaxf(fmaf(a0, inv, obv.x), 0.f);
    float o1 = fmaxf(fmaf(a1, inv, obv.y), 0.f);
    *(float2*)&Y[(size_t)n * HDIM + (lane << 1)] = make_float2(o0, o1);
}

// ---------------- fused BN stats + per-graph sum pool (single pass over Y) ----------------
__global__ __launch_bounds__(256) void k_stats_pool(const float* __restrict__ Y,
                                                    const int* __restrict__ seg,
                                                    float* __restrict__ sums,
                                                    float* __restrict__ sumsq,
                                                    float* __restrict__ pooled) {
    __shared__ float ls[256], lq[256];
    __shared__ int sseg[256];
    int t = threadIdx.x;
    int r0 = blockIdx.x * 256;
    if (r0 + t < N_NODES) sseg[t] = seg[r0 + t];
    __syncthreads();
    int c = t & 127, half = t >> 7;
    int rend = r0 + 256 < N_NODES ? r0 + 256 : N_NODES;
    float s = 0.f, q = 0.f;
    int curg = -1;
    float run = 0.f;
    for (int r = r0 + half; r < rend; r += 2) {
        float v = Y[(size_t)r * HDIM + c];
        s += v;
        q = fmaf(v, v, q);
        int g = sseg[r - r0];
        if (g != curg) {
            if (curg >= 0) atomicAdd(&pooled[curg * HDIM + c], run);
            curg = g;
            run = v;
        } else {
            run += v;
        }
    }
    if (curg >= 0) atomicAdd(&pooled[curg * HDIM + c], run);
    ls[t] = s; lq[t] = q;
    __syncthreads();
    if (t < 128) {
        atomicAdd(&sums[c], ls[t] + ls[t + 128]);
        atomicAdd(&sumsq[c], lq[t] + lq[t + 128]);
    }
}

// ---------------- per-layer head: BN finalize + pooled affine + linear + ReLU + BN ----------------
__global__ __launch_bounds__(256) void k_pool_head(const float* __restrict__ sums,
                                                   const float* __restrict__ sumsq,
                                                   const float* __restrict__ bng,
                                                   const float* __restrict__ bnb,
                                                   const float* __restrict__ pooled,
                                                   const int* __restrict__ gs,
                                                   const float* __restrict__ lw,
                                                   const float* __restrict__ lb,
                                                   const float* __restrict__ lg,
                                                   const float* __restrict__ lbt,
                                                   float* __restrict__ Abuf,
                                                   float* __restrict__ Bbuf,
                                                   float* __restrict__ pbn) {
    __shared__ float sA[HDIM], sB[HDIM];
    __shared__ float pl[G_GRAPHS][HID];
    __shared__ float sc[HID], sh[HID];
    int t = threadIdx.x;
    if (t < HDIM) {
        float mu = sums[t] * (1.f / N_NODES);
        float var = fmaxf(sumsq[t] * (1.f / N_NODES) - mu * mu, 0.f);
        float inv = rsqrtf(var + BN_EPS);
        float a = bng[t] * inv;
        float bsh = bnb[t] - a * mu;
        sA[t] = a; sB[t] = bsh;
        Abuf[t] = a; Bbuf[t] = bsh;  // consumed by next layer's GEMM
    }
    __syncthreads();
    #pragma unroll
    for (int i = 0; i < (G_GRAPHS * HID) / 256; ++i) {  // 8
        int o = t + 256 * i;
        int row = o >> 5, col = o & 31;
        float cnt = (float)(gs[row + 1] - gs[row]);
        float acc = lb[col];
        for (int k = 0; k < HDIM; ++k) {
            float pin = fmaf(sA[k], pooled[row * HDIM + k], cnt * sB[k]);
            acc = fmaf(pin, lw[k * HID + col], acc);
        }
        pl[row][col] = fmaxf(acc, 0.f);
    }
    __syncthreads();
    if (t < HID) {
        float s = 0.f, q = 0.f;
        for (int r = 0; r < G_GRAPHS; ++r) {
            float v = pl[r][t];
            s += v; q = fmaf(v, v, q);
        }
        float mu = s * (1.f / G_GRAPHS);
        float var = fmaxf(q * (1.f / G_GRAPHS) - mu * mu, 0.f);
        float inv = rsqrtf(var + BN_EPS);
        float a = lg[t] * inv;
        sc[t] = a;
        sh[t] = lbt[t] - a * mu;
    }
    __syncthreads();
    #pragma unroll
    for (int i = 0; i < 8; ++i) {
        int o = t + 256 * i;
        int row = o >> 5, col = o & 31;
        pbn[o] = fmaf(pl[row][col], sc[col], sh[col]);
    }
}

// ---------------- final MLP head + log_softmax ----------------
__global__ __launch_bounds__(256) void k_head(const float* __restrict__ pbn0,
                                              const float* __restrict__ pbn1,
                                              const float* __restrict__ pbn2,
                                              const float* __restrict__ mw1,
                                              const float* __restrict__ mg,
                                              const float* __restrict__ mb,
                                              const float* __restrict__ mw2,
                                              float* __restrict__ out) {
    __shared__ float hm[G_GRAPHS][HID];
    __shared__ float sc[HID], sh[HID];
    __shared__ float lgt[G_GRAPHS][NCLS];
    int t = threadIdx.x;
    const float* ph[3] = {pbn0, pbn1, pbn2};
    #pragma unroll
    for (int i = 0; i < 8; ++i) {
        int o = t + 256 * i;
        int row = o >> 5, col = o & 31;
        float acc = 0.f;
        for (int kb = 0; kb < 3; ++kb)
            for (int k = 0; k < HID; ++k)
                acc = fmaf(ph[kb][row * HID + k], mw1[(kb * HID + k) * HID + col], acc);
        hm[row][col] = acc;
    }
    __syncthreads();
    if (t < HID) {
        float s = 0.f, q = 0.f;
        for (int r = 0; r < G_GRAPHS; ++r) {
            float v = hm[r][t];
            s += v; q = fmaf(v, v, q);
        }
        float mu = s * (1.f / G_GRAPHS);
        float var = fmaxf(q * (1.f / G_GRAPHS) - mu * mu, 0.f);
        float inv = rsqrtf(var + BN_EPS);
        float a = mg[t] * inv;
        sc[t] = a;
        sh[t] = mb[t] - a * mu;
    }
    __syncthreads();
    #pragma unroll
    for (int i = 0; i < 8; ++i) {
        int o = t + 256 * i;
        int row = o >> 5, col = o & 31;
        hm[row][col] = fmaxf(fmaf(hm[row][col], sc[col], sh[col]), 0.f);
    }
    __syncthreads();
    #pragma unroll
    for (int i = 0; i < 3; ++i) {
        int o = t + 256 * i;
        if (o < G_GRAPHS * NCLS) {
            int row = o / NCLS, col = o % NCLS;
            float acc = 0.f;
            for (int k = 0; k < HID; ++k) acc = fmaf(hm[row][k], mw2[k * NCLS + col], acc);
            lgt[row][col] = acc;
        }
    }
    __syncthreads();
    if (t < G_GRAPHS) {
        float mx = -INFINITY;
        for (int c = 0; c < NCLS; ++c) mx = fmaxf(mx, lgt[t][c]);
        float s = 0.f;
        for (int c = 0; c < NCLS; ++c) s += expf(lgt[t][c] - mx);
        float lse = mx + logf(s);
        for (int c = 0; c < NCLS; ++c) out[t * NCLS + c] = lgt[t][c] - lse;
    }
}

extern "C" void kernel_launch(void* const* d_in, const int* in_sizes, int n_in,
                              void* d_out, int out_size, void* d_ws, size_t ws_size,
                              hipStream_t stream) {
    (void)in_sizes; (void)n_in; (void)out_size; (void)ws_size;
    const float* feat = (const float*)d_in[0];
    const int* src = (const int*)d_in[1];
    const int* dst = (const int*)d_in[2];
    const int* seg = (const int*)d_in[3];
    auto LP = [&](int l, int j) { return (const float*)d_in[4 + 10 * l + j]; };
    const float* mw1 = (const float*)d_in[34];
    const float* mg  = (const float*)d_in[35];
    const float* mb  = (const float*)d_in[36];
    const float* mw2 = (const float*)d_in[37];

    char* p = (char*)d_ws;
    auto alloc = [&](size_t bytes) { char* r = p; p += (bytes + 255) & ~(size_t)255; return r; };
    unsigned short* Hb = (unsigned short*)alloc((size_t)N_NODES * HDIM * 2);
    float* y      = (float*)alloc((size_t)N_NODES * HDIM * 4);
    int*   ssrc   = (int*)alloc((size_t)N_EDGES * 4);
    int*   rp     = (int*)alloc((size_t)(N_NODES + 1) * 4);
    int*   cursor = (int*)alloc((size_t)N_NODES * 4);
    int*   deg    = (int*)alloc((size_t)N_NODES * 4);
    float* statsAll = (float*)alloc((size_t)3 * STATS_STRIDE * 4);  // adjacent to deg: one memset
    float* Abuf   = (float*)alloc(HDIM * 4);
    float* Bbuf   = (float*)alloc(HDIM * 4);
    float* pbn    = (float*)alloc((size_t)3 * G_GRAPHS * HID * 4);
    int*   gs     = (int*)alloc((size_t)(G_GRAPHS + 1) * 4);
    int*   bsum   = (int*)alloc((size_t)NB_SCAN * 4);
    int*   boff   = (int*)alloc((size_t)NB_SCAN * 4);
    unsigned short* WL = (unsigned short*)alloc((size_t)3 * HDIM * HDIM * 2);

    // zero deg + all per-layer stats in one shot (they are adjacent in ws)
    size_t zspan = (size_t)((char*)(statsAll + 3 * STATS_STRIDE) - (char*)deg);
    hipMemsetAsync(deg, 0, zspan, stream);

    // CSR build (deterministic per call)
    k_count_deg<<<(N_EDGES + 255) / 256, 256, 0, stream>>>(dst, deg);
    k_blocksum<<<NB_SCAN, 256, 0, stream>>>(deg, bsum);
    k_scan_bsums<<<1, 256, 0, stream>>>(bsum, boff);
    k_rowptr<<<NB_SCAN, 256, 0, stream>>>(deg, boff, rp, cursor);
    k_fill<<<(N_EDGES + 255) / 256, 256, 0, stream>>>(src, dst, cursor, ssrc);
    k_graph_bounds<<<1, 128, 0, stream>>>(seg, gs);
    for (int l = 0; l < 3; ++l)
        k_prep_w<<<16, 256, 0, stream>>>(LP(l, 0), WL + (size_t)l * HDIM * HDIM);

    const float* x = feat;
    for (int l = 0; l < 3; ++l) {
        float* sums   = statsAll + (size_t)l * STATS_STRIDE;
        float* sumsq  = sums + 128;
        float* pooled = sums + 256;
        k_gemm_mfma<<<(N_NODES + 63) / 64, 256, 0, stream>>>(
            x, WL + (size_t)l * HDIM * HDIM, LP(l, 1), Abuf, Bbuf, l > 0 ? 1 : 0, Hb);
        k_edge<<<(N_NODES + 3) / 4, 256, 0, stream>>>(Hb, rp, ssrc, LP(l, 2), LP(l, 3), y);
        k_stats_pool<<<NB_SCAN, 256, 0, stream>>>(y, seg, sums, sumsq, pooled);
        k_pool_head<<<1, 256, 0, stream>>>(sums, sumsq, LP(l, 4), LP(l, 5), pooled, gs,
                                           LP(l, 6), LP(l, 7), LP(l, 8), LP(l, 9),
                                           Abuf, Bbuf, pbn + (size_t)l * G_GRAPHS * HID);
        x = y;  // next layer folds BN(y) via Abuf/Bbuf inside the GEMM
    }
    k_head<<<1, 256, 0, stream>>>(pbn, pbn + G_GRAPHS * HID, pbn + 2 * G_GRAPHS * HID,
                                  mw1, mg, mb, mw2, (float*)d_out);
}

// Round 4
// 539.201 us; speedup vs baseline: 2.1732x; 1.0148x over previous
//
#include <hip/hip_runtime.h>
#include <math.h>

#define N_NODES 50000
#define N_EDGES 800000
#define G_GRAPHS 64
#define HDIM 128
#define HID 32
#define NCLS 10
#define BN_EPS 1e-5f
#define SLOPE 0.2f
#define NB_SCAN 196  // ceil(N_NODES/256)
#define STATS_STRIDE (256 + G_GRAPHS * HDIM)
#define DEFER_THR 8.0f

typedef __attribute__((ext_vector_type(8))) short bf16x8;
typedef __attribute__((ext_vector_type(4))) float f32x4;

__device__ __forceinline__ float lrelu(float x) { return fmaxf(x, SLOPE * x); }

__device__ __forceinline__ unsigned short f2bf(float x) {
    unsigned int u = __float_as_uint(x);
    u = (u + 0x7fffu + ((u >> 16) & 1u)) >> 16;
    return (unsigned short)u;
}
__device__ __forceinline__ unsigned int pk2bf(float lo, float hi) {
    unsigned int r;
    asm("v_cvt_pk_bf16_f32 %0, %1, %2" : "=v"(r) : "v"(lo), "v"(hi));
    return r;
}
__device__ __forceinline__ float2 up2(unsigned int u) {
    return make_float2(__uint_as_float(u << 16), __uint_as_float(u & 0xffff0000u));
}
__device__ __forceinline__ float bf2f(unsigned short u) {
    return __uint_as_float((unsigned int)u << 16);
}
// W[k][c] -> MFMA B-fragment slot for 16x16x32 bf16
__device__ __forceinline__ int wl_index(int k, int c) {
    int lane = ((k >> 3) & 3) * 16 + (c & 15);
    return (((k >> 5) * 8 + (c >> 4)) * 64 + lane) * 8 + (k & 7);
}

// ---------------- CSR build ----------------
__global__ void k_count_deg(const int* __restrict__ dst, int* __restrict__ deg) {
    int i = blockIdx.x * blockDim.x + threadIdx.x;
    if (i < N_EDGES) atomicAdd(&deg[dst[i]], 1);
}

// blocks 0..NB_SCAN-1: per-block degree sums; block NB_SCAN: graph bounds
__global__ __launch_bounds__(256) void k_blocksum(const int* __restrict__ deg,
                                                  int* __restrict__ bsum,
                                                  const int* __restrict__ seg,
                                                  int* __restrict__ gs) {
    int t = threadIdx.x;
    if (blockIdx.x == NB_SCAN) {
        if (t <= G_GRAPHS) {
            int g = t;
            int lo = 0, hi = N_NODES;
            while (lo < hi) {
                int mid = (lo + hi) >> 1;
                if (seg[mid] < g) lo = mid + 1; else hi = mid;
            }
            gs[g] = lo;
        }
        return;
    }
    __shared__ int ls[256];
    int i = blockIdx.x * 256 + t;
    int v = i < N_NODES ? deg[i] : 0;
    ls[t] = v;
    __syncthreads();
    for (int off = 128; off > 0; off >>= 1) {
        if (t < off) ls[t] += ls[t + off];
        __syncthreads();
    }
    if (t == 0) bsum[blockIdx.x] = ls[0];
}

// each block: scan bsum locally for its offset, then block-local exclusive scan of deg
__global__ __launch_bounds__(256) void k_rowptr(const int* __restrict__ deg,
                                                const int* __restrict__ bsum,
                                                int* __restrict__ row_ptr,
                                                int* __restrict__ cursor) {
    __shared__ int ls[256];
    int t = threadIdx.x;
    int bv = t < NB_SCAN ? bsum[t] : 0;
    ls[t] = bv;
    __syncthreads();
    for (int off = 1; off < 256; off <<= 1) {
        int u = t >= off ? ls[t - off] : 0;
        __syncthreads();
        ls[t] += u;
        __syncthreads();
    }
    int boffv = blockIdx.x > 0 ? ls[blockIdx.x - 1] : 0;  // exclusive prefix of this block
    __syncthreads();
    int i = blockIdx.x * 256 + t;
    int v = i < N_NODES ? deg[i] : 0;
    ls[t] = v;
    __syncthreads();
    for (int off = 1; off < 256; off <<= 1) {
        int u = t >= off ? ls[t - off] : 0;
        __syncthreads();
        ls[t] += u;
        __syncthreads();
    }
    int excl = ls[t] - v + boffv;
    if (i < N_NODES) {
        row_ptr[i] = excl;
        cursor[i] = excl;
    }
    if (i == N_NODES - 1) row_ptr[N_NODES] = excl + v;
}

__global__ void k_fill(const int* __restrict__ src, const int* __restrict__ dst,
                       int* __restrict__ cursor, int* __restrict__ ssrc) {
    int i = blockIdx.x * blockDim.x + threadIdx.x;
    if (i < N_EDGES) {
        int p = atomicAdd(&cursor[dst[i]], 1);
        ssrc[p] = src[i];
    }
}

// ---------------- layer-0 W prep (no BN fold) ----------------
__global__ __launch_bounds__(256) void k_prep_w(const float* __restrict__ W,
                                                unsigned short* __restrict__ WL) {
    for (int idx = blockIdx.x * 256 + threadIdx.x; idx < HDIM * HDIM; idx += 16 * 256) {
        int k = idx >> 7, c = idx & 127;
        WL[wl_index(k, c)] = f2bf(W[idx]);
    }
}

// ---------------- MFMA GEMM: Hb = bf16( X @ W' + fb' ), no LDS, no affine ----------------
template <bool XF32>
__global__ __launch_bounds__(256) void k_gemm_mfma(const void* __restrict__ Xv,
                                                   const unsigned short* __restrict__ WL,
                                                   const float* __restrict__ fb,
                                                   unsigned short* __restrict__ Hb) {
    int t = threadIdx.x;
    int w = t >> 6, lane = t & 63;
    int i16 = lane & 15, kg = lane >> 4;
    int r0w = blockIdx.x * 64 + w * 16;
    int row = r0w + i16;
    int rowc = row < N_NODES ? row : N_NODES - 1;

    f32x4 acc[8];
    #pragma unroll
    for (int cs = 0; cs < 8; ++cs) acc[cs] = (f32x4){0.f, 0.f, 0.f, 0.f};

    #pragma unroll
    for (int ks = 0; ks < 4; ++ks) {
        union { uint4 u; bf16x8 s; } af;
        if (XF32) {
            const float* xp = (const float*)Xv + (size_t)rowc * HDIM + ks * 32 + kg * 8;
            float4 v0 = *(const float4*)xp;
            float4 v1 = *(const float4*)(xp + 4);
            af.u.x = pk2bf(v0.x, v0.y);
            af.u.y = pk2bf(v0.z, v0.w);
            af.u.z = pk2bf(v1.x, v1.y);
            af.u.w = pk2bf(v1.z, v1.w);
        } else {
            const unsigned short* xp = (const unsigned short*)Xv + (size_t)rowc * HDIM + ks * 32 + kg * 8;
            af.u = *(const uint4*)xp;
        }
        #pragma unroll
        for (int cs = 0; cs < 8; ++cs) {
            union { uint4 u; bf16x8 s; } bw;
            bw.u = *(const uint4*)&WL[(((ks << 3) + cs) * 64 + lane) * 8];
            acc[cs] = __builtin_amdgcn_mfma_f32_16x16x32_bf16(af.s, bw.s, acc[cs], 0, 0, 0);
        }
    }

    // D: col = cs*16 + (lane&15), row = r0w + (lane>>4)*4 + p
    #pragma unroll
    for (int cs = 0; cs < 8; ++cs) {
        int col = cs * 16 + i16;
        float bias = fb[col];
        #pragma unroll
        for (int p = 0; p < 4; ++p) {
            int r = r0w + kg * 4 + p;
            if (r < N_NODES) Hb[(size_t)r * HDIM + col] = f2bf(acc[cs][p] + bias);
        }
    }
}

// ---------------- fused edge kernel: bf16 gathers, 2-unroll, defer-max softmax ----------------
__global__ __launch_bounds__(256) void k_edge(const unsigned short* __restrict__ Hb,
                                              const int* __restrict__ row_ptr,
                                              const int* __restrict__ ssrc,
                                              const float* __restrict__ attn,
                                              const float* __restrict__ ob,
                                              unsigned short* __restrict__ Yb) {
    int wid = blockIdx.x * 4 + (threadIdx.x >> 6);
    int lane = threadIdx.x & 63;
    if (wid >= N_NODES) return;
    const int n = wid;
    float2 er = up2(*(const unsigned int*)&Hb[(size_t)n * HDIM + (lane << 1)]);
    float2 at = *(const float2*)&attn[lane << 1];
    float2 obv = *(const float2*)&ob[lane << 1];
    int beg = row_ptr[n], end = row_ptr[n + 1];

    float m = -INFINITY, den = 0.f, a0 = 0.f, a1 = 0.f;

    unsigned int u0 = 0, u1 = 0;
    int j = beg;
    if (j + 1 < end) {
        int s0 = ssrc[j], s1 = ssrc[j + 1];
        u0 = *(const unsigned int*)&Hb[(size_t)s0 * HDIM + (lane << 1)];
        u1 = *(const unsigned int*)&Hb[(size_t)s1 * HDIM + (lane << 1)];
    }
    while (j + 1 < end) {
        int jn = j + 2;
        unsigned int w0 = u0, w1 = u1;
        if (jn + 1 < end) {
            int t0 = ssrc[jn], t1 = ssrc[jn + 1];
            u0 = *(const unsigned int*)&Hb[(size_t)t0 * HDIM + (lane << 1)];
            u1 = *(const unsigned int*)&Hb[(size_t)t1 * HDIM + (lane << 1)];
        }
        float2 el0 = up2(w0), el1 = up2(w1);
        float p0 = fmaf(lrelu(el0.x + er.x), at.x, lrelu(el0.y + er.y) * at.y);
        float p1 = fmaf(lrelu(el1.x + er.x), at.x, lrelu(el1.y + er.y) * at.y);
        p0 += __shfl_xor(p0, 1); p1 += __shfl_xor(p1, 1);
        p0 += __shfl_xor(p0, 2); p1 += __shfl_xor(p1, 2);
        p0 += __shfl_xor(p0, 4); p1 += __shfl_xor(p1, 4);
        p0 += __shfl_xor(p0, 8); p1 += __shfl_xor(p1, 8);
        float pm = fmaxf(p0, p1);
        if (__all(pm - m <= DEFER_THR)) {  // defer-max: no rescale (T13)
            float q0 = __expf(p0 - m), q1 = __expf(p1 - m);
            den += q0 + q1;
            a0 += fmaf(el0.x, q0, el1.x * q1);
            a1 += fmaf(el0.y, q0, el1.y * q1);
        } else {
            float nm = fmaxf(m, pm);
            float r = __expf(m - nm);
            float q0 = __expf(p0 - nm), q1 = __expf(p1 - nm);
            den = fmaf(den, r, q0 + q1);
            a0 = fmaf(a0, r, fmaf(el0.x, q0, el1.x * q1));
            a1 = fmaf(a1, r, fmaf(el0.y, q0, el1.y * q1));
            m = nm;
        }
        j = jn;
    }
    if (j < end) {  // tail (also the deg==1 case)
        int s = ssrc[j];
        float2 el = up2(*(const unsigned int*)&Hb[(size_t)s * HDIM + (lane << 1)]);
        float p = fmaf(lrelu(el.x + er.x), at.x, lrelu(el.y + er.y) * at.y);
        p += __shfl_xor(p, 1);
        p += __shfl_xor(p, 2);
        p += __shfl_xor(p, 4);
        p += __shfl_xor(p, 8);
        if (__all(p - m <= DEFER_THR)) {
            float q = __expf(p - m);
            den += q;
            a0 = fmaf(el.x, q, a0);
            a1 = fmaf(el.y, q, a1);
        } else {
            float nm = fmaxf(m, p);
            float r = __expf(m - nm);
            float q = __expf(p - nm);
            den = fmaf(den, r, q);
            a0 = fmaf(a0, r, el.x * q);
            a1 = fmaf(a1, r, el.y * q);
        }
    }
    float inv = den > 0.f ? 1.f / den : 0.f;
    float o0 = fmaxf(fmaf(a0, inv, obv.x), 0.f);
    float o1 = fmaxf(fmaf(a1, inv, obv.y), 0.f);
    *(unsigned int*)&Yb[(size_t)n * HDIM + (lane << 1)] = pk2bf(o0, o1);
}

// ---------------- fused BN stats + per-graph sum pool (single bf16 pass over Y) ----------------
__global__ __launch_bounds__(256) void k_stats_pool(const unsigned short* __restrict__ Yb,
                                                    const int* __restrict__ seg,
                                                    float* __restrict__ sums,
                                                    float* __restrict__ sumsq,
                                                    float* __restrict__ pooled) {
    __shared__ float4 red[256];
    __shared__ int sseg[256];
    int t = threadIdx.x;
    int r0 = blockIdx.x * 256;
    if (r0 + t < N_NODES) sseg[t] = seg[r0 + t];
    __syncthreads();
    int c4 = t & 31, rh = t >> 5;  // 4 channels per thread, 8-way row split
    int rend = r0 + 256 < N_NODES ? r0 + 256 : N_NODES;
    float sx = 0.f, sy = 0.f, sz = 0.f, sw = 0.f;
    float qx = 0.f, qy = 0.f, qz = 0.f, qw = 0.f;
    int curg = -1;
    float rx = 0.f, ry = 0.f, rz = 0.f, rw = 0.f;
    for (int r = r0 + rh; r < rend; r += 8) {
        ushort4 v = *(const ushort4*)&Yb[(size_t)r * HDIM + c4 * 4];
        float x0 = bf2f(v.x), x1 = bf2f(v.y), x2 = bf2f(v.z), x3 = bf2f(v.w);
        sx += x0; sy += x1; sz += x2; sw += x3;
        qx = fmaf(x0, x0, qx); qy = fmaf(x1, x1, qy);
        qz = fmaf(x2, x2, qz); qw = fmaf(x3, x3, qw);
        int g = sseg[r - r0];
        if (g != curg) {
            if (curg >= 0) {
                float* pp = &pooled[curg * HDIM + c4 * 4];
                atomicAdd(pp + 0, rx); atomicAdd(pp + 1, ry);
                atomicAdd(pp + 2, rz); atomicAdd(pp + 3, rw);
            }
            curg = g;
            rx = x0; ry = x1; rz = x2; rw = x3;
        } else {
            rx += x0; ry += x1; rz += x2; rw += x3;
        }
    }
    if (curg >= 0) {
        float* pp = &pooled[curg * HDIM + c4 * 4];
        atomicAdd(pp + 0, rx); atomicAdd(pp + 1, ry);
        atomicAdd(pp + 2, rz); atomicAdd(pp + 3, rw);
    }
    red[t] = make_float4(sx, sy, sz, sw);
    __syncthreads();
    if (rh == 0) {
        float4 tot = red[c4];
        #pragma unroll
        for (int i = 1; i < 8; ++i) {
            float4 o = red[i * 32 + c4];
            tot.x += o.x; tot.y += o.y; tot.z += o.z; tot.w += o.w;
        }
        float* sp = &sums[c4 * 4];
        atomicAdd(sp + 0, tot.x); atomicAdd(sp + 1, tot.y);
        atomicAdd(sp + 2, tot.z); atomicAdd(sp + 3, tot.w);
    }
    __syncthreads();
    red[t] = make_float4(qx, qy, qz, qw);
    __syncthreads();
    if (rh == 0) {
        float4 tot = red[c4];
        #pragma unroll
        for (int i = 1; i < 8; ++i) {
            float4 o = red[i * 32 + c4];
            tot.x += o.x; tot.y += o.y; tot.z += o.z; tot.w += o.w;
        }
        float* sp = &sumsq[c4 * 4];
        atomicAdd(sp + 0, tot.x); atomicAdd(sp + 1, tot.y);
        atomicAdd(sp + 2, tot.z); atomicAdd(sp + 3, tot.w);
    }
}

// ---------------- per-layer head: BN finalize + W'(next) fold + pooled head (+final MLP) ----------------
__global__ __launch_bounds__(256) void k_pool_head(const float* __restrict__ sums,
                                                   const float* __restrict__ sumsq,
                                                   const float* __restrict__ bng,
                                                   const float* __restrict__ bnb,
                                                   const float* __restrict__ pooled,
                                                   const int* __restrict__ gs,
                                                   const float* __restrict__ lw,
                                                   const float* __restrict__ lb,
                                                   const float* __restrict__ lg,
                                                   const float* __restrict__ lbt,
                                                   const float* __restrict__ Wnext,
                                                   const float* __restrict__ fbnext,
                                                   unsigned short* __restrict__ WLnext,
                                                   float* __restrict__ Fbnext,
                                                   float* __restrict__ pbn,
                                                   int final_head,
                                                   const float* __restrict__ pbn_all,
                                                   const float* __restrict__ mw1,
                                                   const float* __restrict__ mg,
                                                   const float* __restrict__ mb,
                                                   const float* __restrict__ mw2,
                                                   float* __restrict__ out) {
    __shared__ float sA[HDIM], sB[HDIM];
    __shared__ float pl[G_GRAPHS][HID];
    __shared__ float hm[G_GRAPHS][HID];
    __shared__ float sc[HID], sh[HID];
    __shared__ float lgt[G_GRAPHS][NCLS];
    int t = threadIdx.x;
    if (t < HDIM) {
        float mu = sums[t] * (1.f / N_NODES);
        float var = fmaxf(sumsq[t] * (1.f / N_NODES) - mu * mu, 0.f);
        float inv = rsqrtf(var + BN_EPS);
        float a = bng[t] * inv;
        sA[t] = a;
        sB[t] = bnb[t] - a * mu;
    }
    __syncthreads();
    // fold this layer's BN into the NEXT layer's weights: W' = diag(A)W, fb' = fb + B@W
    if (WLnext) {
        for (int idx = t; idx < HDIM * HDIM; idx += 256) {
            int k = idx >> 7, c = idx & 127;
            WLnext[wl_index(k, c)] = f2bf(sA[k] * Wnext[idx]);
        }
        if (t < HDIM) {
            float a = fbnext[t];
            for (int k = 0; k < HDIM; ++k) a = fmaf(sB[k], Wnext[k * HDIM + t], a);
            Fbnext[t] = a;
        }
    }
    // pooled head: BN(pool) -> linear -> relu
    #pragma unroll
    for (int i = 0; i < (G_GRAPHS * HID) / 256; ++i) {  // 8
        int o = t + 256 * i;
        int row = o >> 5, col = o & 31;
        float cnt = (float)(gs[row + 1] - gs[row]);
        float acc = lb[col];
        for (int k = 0; k < HDIM; ++k) {
            float pin = fmaf(sA[k], pooled[row * HDIM + k], cnt * sB[k]);
            acc = fmaf(pin, lw[k * HID + col], acc);
        }
        pl[row][col] = fmaxf(acc, 0.f);
    }
    __syncthreads();
    if (t < HID) {
        float s = 0.f, q = 0.f;
        for (int r = 0; r < G_GRAPHS; ++r) {
            float v = pl[r][t];
            s += v; q = fmaf(v, v, q);
        }
        float mu = s * (1.f / G_GRAPHS);
        float var = fmaxf(q * (1.f / G_GRAPHS) - mu * mu, 0.f);
        float inv = rsqrtf(var + BN_EPS);
        float a = lg[t] * inv;
        sc[t] = a;
        sh[t] = lbt[t] - a * mu;
    }
    __syncthreads();
    #pragma unroll
    for (int i = 0; i < 8; ++i) {
        int o = t + 256 * i;
        int row = o >> 5, col = o & 31;
        float v = fmaf(pl[row][col], sc[col], sh[col]);
        pbn[o] = v;
        pl[row][col] = v;  // keep post-BN local for the fused final head
    }
    if (!final_head) return;

    // ---------------- final MLP head + log_softmax (layer 2 only) ----------------
    __syncthreads();
    #pragma unroll
    for (int i = 0; i < 8; ++i) {
        int o = t + 256 * i;
        int row = o >> 5, col = o & 31;
        float acc = 0.f;
        for (int kb = 0; kb < 2; ++kb)
            for (int k = 0; k < HID; ++k)
                acc = fmaf(pbn_all[kb * G_GRAPHS * HID + row * HID + k],
                           mw1[(kb * HID + k) * HID + col], acc);
        for (int k = 0; k < HID; ++k)
            acc = fmaf(pl[row][k], mw1[(2 * HID + k) * HID + col], acc);
        hm[row][col] = acc;
    }
    __syncthreads();
    if (t < HID) {
        float s = 0.f, q = 0.f;
        for (int r = 0; r < G_GRAPHS; ++r) {
            float v = hm[r][t];
            s += v; q = fmaf(v, v, q);
        }
        float mu = s * (1.f / G_GRAPHS);
        float var = fmaxf(q * (1.f / G_GRAPHS) - mu * mu, 0.f);
        float inv = rsqrtf(var + BN_EPS);
        float a = mg[t] * inv;
        sc[t] = a;
        sh[t] = mb[t] - a * mu;
    }
    __syncthreads();
    #pragma unroll
    for (int i = 0; i < 8; ++i) {
        int o = t + 256 * i;
        int row = o >> 5, col = o & 31;
        hm[row][col] = fmaxf(fmaf(hm[row][col], sc[col], sh[col]), 0.f);
    }
    __syncthreads();
    #pragma unroll
    for (int i = 0; i < 3; ++i) {
        int o = t + 256 * i;
        if (o < G_GRAPHS * NCLS) {
            int row = o / NCLS, col = o % NCLS;
            float acc = 0.f;
            for (int k = 0; k < HID; ++k) acc = fmaf(hm[row][k], mw2[k * NCLS + col], acc);
            lgt[row][col] = acc;
        }
    }
    __syncthreads();
    if (t < G_GRAPHS) {
        float mx = -INFINITY;
        for (int c = 0; c < NCLS; ++c) mx = fmaxf(mx, lgt[t][c]);
        float s = 0.f;
        for (int c = 0; c < NCLS; ++c) s += expf(lgt[t][c] - mx);
        float lse = mx + logf(s);
        for (int c = 0; c < NCLS; ++c) out[t * NCLS + c] = lgt[t][c] - lse;
    }
}

extern "C" void kernel_launch(void* const* d_in, const int* in_sizes, int n_in,
                              void* d_out, int out_size, void* d_ws, size_t ws_size,
                              hipStream_t stream) {
    (void)in_sizes; (void)n_in; (void)out_size; (void)ws_size;
    const float* feat = (const float*)d_in[0];
    const int* src = (const int*)d_in[1];
    const int* dst = (const int*)d_in[2];
    const int* seg = (const int*)d_in[3];
    auto LP = [&](int l, int j) { return (const float*)d_in[4 + 10 * l + j]; };
    const float* mw1 = (const float*)d_in[34];
    const float* mg  = (const float*)d_in[35];
    const float* mb  = (const float*)d_in[36];
    const float* mw2 = (const float*)d_in[37];

    char* p = (char*)d_ws;
    auto alloc = [&](size_t bytes) { char* r = p; p += (bytes + 255) & ~(size_t)255; return r; };
    unsigned short* Hb = (unsigned short*)alloc((size_t)N_NODES * HDIM * 2);
    unsigned short* Yb = (unsigned short*)alloc((size_t)N_NODES * HDIM * 2);
    int*   ssrc   = (int*)alloc((size_t)N_EDGES * 4);
    int*   rp     = (int*)alloc((size_t)(N_NODES + 1) * 4);
    int*   cursor = (int*)alloc((size_t)N_NODES * 4);
    int*   deg    = (int*)alloc((size_t)N_NODES * 4);
    float* statsAll = (float*)alloc((size_t)3 * STATS_STRIDE * 4);  // adjacent to deg: one memset
    float* pbn    = (float*)alloc((size_t)3 * G_GRAPHS * HID * 4);
    int*   gs     = (int*)alloc((size_t)(G_GRAPHS + 1) * 4);
    int*   bsum   = (int*)alloc((size_t)NB_SCAN * 4);
    unsigned short* WL = (unsigned short*)alloc((size_t)3 * HDIM * HDIM * 2);
    float* Fb     = (float*)alloc((size_t)3 * HDIM * 4);  // folded biases (layers 1,2)

    // zero deg + all per-layer stats in one shot (adjacent in ws)
    size_t zspan = (size_t)((char*)(statsAll + 3 * STATS_STRIDE) - (char*)deg);
    hipMemsetAsync(deg, 0, zspan, stream);

    // CSR build + layer-0 W prep
    k_prep_w<<<16, 256, 0, stream>>>(LP(0, 0), WL);
    k_count_deg<<<(N_EDGES + 255) / 256, 256, 0, stream>>>(dst, deg);
    k_blocksum<<<NB_SCAN + 1, 256, 0, stream>>>(deg, bsum, seg, gs);
    k_rowptr<<<NB_SCAN, 256, 0, stream>>>(deg, bsum, rp, cursor);
    k_fill<<<(N_EDGES + 255) / 256, 256, 0, stream>>>(src, dst, cursor, ssrc);

    const void* x = feat;
    for (int l = 0; l < 3; ++l) {
        float* sums   = statsAll + (size_t)l * STATS_STRIDE;
        float* sumsq  = sums + 128;
        float* pooled = sums + 256;
        const float* bias = l == 0 ? LP(0, 1) : Fb + (size_t)l * HDIM;
        if (l == 0)
            k_gemm_mfma<true><<<(N_NODES + 63) / 64, 256, 0, stream>>>(x, WL, bias, Hb);
        else
            k_gemm_mfma<false><<<(N_NODES + 63) / 64, 256, 0, stream>>>(
                x, WL + (size_t)l * HDIM * HDIM, bias, Hb);
        k_edge<<<(N_NODES + 3) / 4, 256, 0, stream>>>(Hb, rp, ssrc, LP(l, 2), LP(l, 3), Yb);
        k_stats_pool<<<NB_SCAN, 256, 0, stream>>>(Yb, seg, sums, sumsq, pooled);
        int isLast = (l == 2);
        k_pool_head<<<1, 256, 0, stream>>>(
            sums, sumsq, LP(l, 4), LP(l, 5), pooled, gs,
            LP(l, 6), LP(l, 7), LP(l, 8), LP(l, 9),
            isLast ? nullptr : LP(l + 1, 0), isLast ? nullptr : LP(l + 1, 1),
            isLast ? nullptr : WL + (size_t)(l + 1) * HDIM * HDIM,
            isLast ? nullptr : Fb + (size_t)(l + 1) * HDIM,
            pbn + (size_t)l * G_GRAPHS * HID,
            isLast, pbn, mw1, mg, mb, mw2, (float*)d_out);
        x = Yb;
    }
}

// Round 5
// 472.601 us; speedup vs baseline: 2.4794x; 1.1409x over previous
//
#include <hip/hip_runtime.h>
#include <math.h>

#define N_NODES 50000
#define N_EDGES 800000
#define G_GRAPHS 64
#define HDIM 128
#define HID 32
#define NCLS 10
#define BN_EPS 1e-5f
#define SLOPE 0.2f
#define NB_SCAN 196  // ceil(N_NODES/256)
#define STATS_STRIDE (256 + G_GRAPHS * HDIM)
#define DEFER_THR 8.0f

typedef __attribute__((ext_vector_type(8))) short bf16x8;
typedef __attribute__((ext_vector_type(4))) float f32x4;

__device__ __forceinline__ float lrelu(float x) { return fmaxf(x, SLOPE * x); }

__device__ __forceinline__ unsigned short f2bf(float x) {
    unsigned int u = __float_as_uint(x);
    u = (u + 0x7fffu + ((u >> 16) & 1u)) >> 16;
    return (unsigned short)u;
}
__device__ __forceinline__ unsigned int pk2bf(float lo, float hi) {
    unsigned int r;
    asm("v_cvt_pk_bf16_f32 %0, %1, %2" : "=v"(r) : "v"(lo), "v"(hi));
    return r;
}
__device__ __forceinline__ float2 up2(unsigned int u) {
    return make_float2(__uint_as_float(u << 16), __uint_as_float(u & 0xffff0000u));
}
__device__ __forceinline__ float bf2f(unsigned short u) {
    return __uint_as_float((unsigned int)u << 16);
}
// W[k][c] -> MFMA B-fragment slot for 16x16x32 bf16
__device__ __forceinline__ int wl_index(int k, int c) {
    int lane = ((k >> 3) & 3) * 16 + (c & 15);
    return (((k >> 5) * 8 + (c >> 4)) * 64 + lane) * 8 + (k & 7);
}

// ---------------- CSR build ----------------
__global__ void k_count_deg(const int* __restrict__ dst, int* __restrict__ deg) {
    int i = blockIdx.x * blockDim.x + threadIdx.x;
    if (i < N_EDGES) atomicAdd(&deg[dst[i]], 1);
}

// blocks 0..NB_SCAN-1: per-block degree sums; block NB_SCAN: graph bounds
__global__ __launch_bounds__(256) void k_blocksum(const int* __restrict__ deg,
                                                  int* __restrict__ bsum,
                                                  const int* __restrict__ seg,
                                                  int* __restrict__ gs) {
    int t = threadIdx.x;
    if (blockIdx.x == NB_SCAN) {
        if (t <= G_GRAPHS) {
            int g = t;
            int lo = 0, hi = N_NODES;
            while (lo < hi) {
                int mid = (lo + hi) >> 1;
                if (seg[mid] < g) lo = mid + 1; else hi = mid;
            }
            gs[g] = lo;
        }
        return;
    }
    __shared__ int ls[256];
    int i = blockIdx.x * 256 + t;
    int v = i < N_NODES ? deg[i] : 0;
    ls[t] = v;
    __syncthreads();
    for (int off = 128; off > 0; off >>= 1) {
        if (t < off) ls[t] += ls[t + off];
        __syncthreads();
    }
    if (t == 0) bsum[blockIdx.x] = ls[0];
}

// each block: scan bsum locally for its offset, then block-local exclusive scan of deg
__global__ __launch_bounds__(256) void k_rowptr(const int* __restrict__ deg,
                                                const int* __restrict__ bsum,
                                                int* __restrict__ row_ptr,
                                                int* __restrict__ cursor) {
    __shared__ int ls[256];
    int t = threadIdx.x;
    int bv = t < NB_SCAN ? bsum[t] : 0;
    ls[t] = bv;
    __syncthreads();
    for (int off = 1; off < 256; off <<= 1) {
        int u = t >= off ? ls[t - off] : 0;
        __syncthreads();
        ls[t] += u;
        __syncthreads();
    }
    int boffv = blockIdx.x > 0 ? ls[blockIdx.x - 1] : 0;  // exclusive prefix of this block
    __syncthreads();
    int i = blockIdx.x * 256 + t;
    int v = i < N_NODES ? deg[i] : 0;
    ls[t] = v;
    __syncthreads();
    for (int off = 1; off < 256; off <<= 1) {
        int u = t >= off ? ls[t - off] : 0;
        __syncthreads();
        ls[t] += u;
        __syncthreads();
    }
    int excl = ls[t] - v + boffv;
    if (i < N_NODES) {
        row_ptr[i] = excl;
        cursor[i] = excl;
    }
    if (i == N_NODES - 1) row_ptr[N_NODES] = excl + v;
}

__global__ void k_fill(const int* __restrict__ src, const int* __restrict__ dst,
                       int* __restrict__ cursor, int* __restrict__ ssrc) {
    int i = blockIdx.x * blockDim.x + threadIdx.x;
    if (i < N_EDGES) {
        int p = atomicAdd(&cursor[dst[i]], 1);
        ssrc[p] = src[i];
    }
}

// ---------------- layer-0 W prep (no BN fold) ----------------
__global__ __launch_bounds__(256) void k_prep_w(const float* __restrict__ W,
                                                unsigned short* __restrict__ WL) {
    for (int idx = blockIdx.x * 256 + threadIdx.x; idx < HDIM * HDIM; idx += 16 * 256) {
        int k = idx >> 7, c = idx & 127;
        WL[wl_index(k, c)] = f2bf(W[idx]);
    }
}

// ---------------- BN-fold into next layer's W: W' = diag(A)W (blocks 0..63), fb' = fb + B@W (block 64) ----------------
__global__ __launch_bounds__(256) void k_fold_w(const float* __restrict__ sums,
                                                const float* __restrict__ sumsq,
                                                const float* __restrict__ bng,
                                                const float* __restrict__ bnb,
                                                const float* __restrict__ Wnext,
                                                const float* __restrict__ fbnext,
                                                unsigned short* __restrict__ WLnext,
                                                float* __restrict__ Fbnext) {
    __shared__ float sA[HDIM], sB[HDIM];
    int t = threadIdx.x;
    if (t < HDIM) {
        float mu = sums[t] * (1.f / N_NODES);
        float var = fmaxf(sumsq[t] * (1.f / N_NODES) - mu * mu, 0.f);
        float inv = rsqrtf(var + BN_EPS);
        float a = bng[t] * inv;
        sA[t] = a;
        sB[t] = bnb[t] - a * mu;
    }
    __syncthreads();
    if (blockIdx.x < 64) {
        int idx = blockIdx.x * 256 + t;  // 64*256 == HDIM*HDIM
        int k = idx >> 7, c = idx & 127;
        WLnext[wl_index(k, c)] = f2bf(sA[k] * Wnext[idx]);
    } else if (t < HDIM) {
        float a = fbnext[t];
        for (int k = 0; k < HDIM; ++k) a = fmaf(sB[k], Wnext[k * HDIM + t], a);
        Fbnext[t] = a;
    }
}

// ---------------- MFMA GEMM: Hb = bf16( X @ W' + fb' ), no LDS ----------------
template <bool XF32>
__global__ __launch_bounds__(256) void k_gemm_mfma(const void* __restrict__ Xv,
                                                   const unsigned short* __restrict__ WL,
                                                   const float* __restrict__ fb,
                                                   unsigned short* __restrict__ Hb) {
    int t = threadIdx.x;
    int w = t >> 6, lane = t & 63;
    int i16 = lane & 15, kg = lane >> 4;
    int r0w = blockIdx.x * 64 + w * 16;
    int row = r0w + i16;
    int rowc = row < N_NODES ? row : N_NODES - 1;

    f32x4 acc[8];
    #pragma unroll
    for (int cs = 0; cs < 8; ++cs) acc[cs] = (f32x4){0.f, 0.f, 0.f, 0.f};

    #pragma unroll
    for (int ks = 0; ks < 4; ++ks) {
        union { uint4 u; bf16x8 s; } af;
        if (XF32) {
            const float* xp = (const float*)Xv + (size_t)rowc * HDIM + ks * 32 + kg * 8;
            float4 v0 = *(const float4*)xp;
            float4 v1 = *(const float4*)(xp + 4);
            af.u.x = pk2bf(v0.x, v0.y);
            af.u.y = pk2bf(v0.z, v0.w);
            af.u.z = pk2bf(v1.x, v1.y);
            af.u.w = pk2bf(v1.z, v1.w);
        } else {
            const unsigned short* xp = (const unsigned short*)Xv + (size_t)rowc * HDIM + ks * 32 + kg * 8;
            af.u = *(const uint4*)xp;
        }
        #pragma unroll
        for (int cs = 0; cs < 8; ++cs) {
            union { uint4 u; bf16x8 s; } bw;
            bw.u = *(const uint4*)&WL[(((ks << 3) + cs) * 64 + lane) * 8];
            acc[cs] = __builtin_amdgcn_mfma_f32_16x16x32_bf16(af.s, bw.s, acc[cs], 0, 0, 0);
        }
    }

    // D: col = cs*16 + (lane&15), row = r0w + (lane>>4)*4 + p
    #pragma unroll
    for (int cs = 0; cs < 8; ++cs) {
        int col = cs * 16 + i16;
        float bias = fb[col];
        #pragma unroll
        for (int p = 0; p < 4; ++p) {
            int r = r0w + kg * 4 + p;
            if (r < N_NODES) Hb[(size_t)r * HDIM + col] = f2bf(acc[cs][p] + bias);
        }
    }
}

// ---------------- fused edge kernel: 4 edge-slots/wave, dwordx4 gathers, slot-parallel online softmax ----------------
__global__ __launch_bounds__(256) void k_edge(const unsigned short* __restrict__ Hb,
                                              const int* __restrict__ row_ptr,
                                              const int* __restrict__ ssrc,
                                              const float* __restrict__ attn,
                                              const float* __restrict__ ob,
                                              unsigned short* __restrict__ Yb) {
    int wid = blockIdx.x * 4 + (threadIdx.x >> 6);
    if (wid >= N_NODES) return;
    int lane = threadIdx.x & 63;
    int slot = lane >> 4, s16 = lane & 15;
    int d0 = s16 << 3;
    int beg = row_ptr[wid], end = row_ptr[wid + 1];
    int deg = end - beg;
    if (deg == 0) {
        if (slot == 0) {
            float4 o0 = *(const float4*)&ob[d0];
            float4 o1 = *(const float4*)&ob[d0 + 4];
            uint4 w;
            w.x = pk2bf(fmaxf(o0.x, 0.f), fmaxf(o0.y, 0.f));
            w.y = pk2bf(fmaxf(o0.z, 0.f), fmaxf(o0.w, 0.f));
            w.z = pk2bf(fmaxf(o1.x, 0.f), fmaxf(o1.y, 0.f));
            w.w = pk2bf(fmaxf(o1.z, 0.f), fmaxf(o1.w, 0.f));
            *(uint4*)&Yb[(size_t)wid * HDIM + d0] = w;
        }
        return;
    }
    float er[8], at[8];
    {
        uint4 e = *(const uint4*)&Hb[(size_t)wid * HDIM + d0];
        unsigned int uu[4] = {e.x, e.y, e.z, e.w};
        #pragma unroll
        for (int i = 0; i < 4; ++i) {
            float2 f = up2(uu[i]);
            er[2 * i] = f.x; er[2 * i + 1] = f.y;
        }
        float4 a0 = *(const float4*)&attn[d0];
        float4 a1 = *(const float4*)&attn[d0 + 4];
        at[0] = a0.x; at[1] = a0.y; at[2] = a0.z; at[3] = a0.w;
        at[4] = a1.x; at[5] = a1.y; at[6] = a1.z; at[7] = a1.w;
    }
    const float NINF = __int_as_float(0xff800000);
    float m = -1e30f, den = 0.f;
    float acc[8] = {0.f, 0.f, 0.f, 0.f, 0.f, 0.f, 0.f, 0.f};
    int nit = (deg + 3) >> 2;
    int j = beg + slot;
    // prefetch pipeline: ssrc 2 ahead, row 1 ahead
    int sa;
    uint4 elc;
    {
        int jc0 = j < end ? j : beg;
        int jc1 = (j + 4) < end ? (j + 4) : beg;
        int s0 = ssrc[jc0];
        sa = ssrc[jc1];
        elc = *(const uint4*)&Hb[(size_t)s0 * HDIM + d0];
    }
    for (int it = 0; it < nit; ++it) {
        int j2 = j + 8;
        int jc2 = j2 < end ? j2 : beg;
        int sb = ssrc[jc2];
        uint4 eln = *(const uint4*)&Hb[(size_t)sa * HDIM + d0];
        bool act = j < end;
        float el[8];
        {
            unsigned int uu[4] = {elc.x, elc.y, elc.z, elc.w};
            #pragma unroll
            for (int i = 0; i < 4; ++i) {
                float2 f = up2(uu[i]);
                el[2 * i] = f.x; el[2 * i + 1] = f.y;
            }
        }
        float p = 0.f;
        #pragma unroll
        for (int d = 0; d < 8; ++d) p = fmaf(lrelu(el[d] + er[d]), at[d], p);
        p += __shfl_xor(p, 1);
        p += __shfl_xor(p, 2);        // 4-lane head-dot reduce
        float e = act ? p : NINF;     // inactive slot-iteration contributes exp -> 0
        if (__all(e - m <= DEFER_THR)) {
            float q = __expf(e - m);
            den += q;
            #pragma unroll
            for (int d = 0; d < 8; ++d) acc[d] = fmaf(el[d], q, acc[d]);
        } else {
            float nm = fmaxf(m, e);
            float r = __expf(m - nm);
            float q = __expf(e - nm);
            den = fmaf(den, r, q);
            #pragma unroll
            for (int d = 0; d < 8; ++d) acc[d] = fmaf(acc[d], r, el[d] * q);
            m = nm;
        }
        elc = eln; sa = sb; j += 4;
    }
    // associative online-softmax merge across the 4 slots
    #pragma unroll
    for (int st = 16; st <= 32; st <<= 1) {
        float m2 = __shfl_xor(m, st);
        float den2 = __shfl_xor(den, st);
        float nm = fmaxf(m, m2);
        float r1 = __expf(m - nm);
        float r2 = __expf(m2 - nm);
        den = den * r1 + den2 * r2;
        #pragma unroll
        for (int d = 0; d < 8; ++d) {
            float a2 = __shfl_xor(acc[d], st);
            acc[d] = acc[d] * r1 + a2 * r2;
        }
        m = nm;
    }
    if (slot == 0) {
        float inv = den > 0.f ? 1.f / den : 0.f;
        float4 o0 = *(const float4*)&ob[d0];
        float4 o1 = *(const float4*)&ob[d0 + 4];
        float o[8] = {o0.x, o0.y, o0.z, o0.w, o1.x, o1.y, o1.z, o1.w};
        float r[8];
        #pragma unroll
        for (int d = 0; d < 8; ++d) r[d] = fmaxf(fmaf(acc[d], inv, o[d]), 0.f);
        uint4 w;
        w.x = pk2bf(r[0], r[1]);
        w.y = pk2bf(r[2], r[3]);
        w.z = pk2bf(r[4], r[5]);
        w.w = pk2bf(r[6], r[7]);
        *(uint4*)&Yb[(size_t)wid * HDIM + d0] = w;
    }
}

// ---------------- fused BN stats + per-graph sum pool (single bf16 pass over Y) ----------------
__global__ __launch_bounds__(256) void k_stats_pool(const unsigned short* __restrict__ Yb,
                                                    const int* __restrict__ seg,
                                                    float* __restrict__ sums,
                                                    float* __restrict__ sumsq,
                                                    float* __restrict__ pooled) {
    __shared__ float4 red[256];
    __shared__ int sseg[256];
    int t = threadIdx.x;
    int r0 = blockIdx.x * 256;
    if (r0 + t < N_NODES) sseg[t] = seg[r0 + t];
    __syncthreads();
    int c4 = t & 31, rh = t >> 5;  // 4 channels per thread, 8-way row split
    int rend = r0 + 256 < N_NODES ? r0 + 256 : N_NODES;
    float sx = 0.f, sy = 0.f, sz = 0.f, sw = 0.f;
    float qx = 0.f, qy = 0.f, qz = 0.f, qw = 0.f;
    int curg = -1;
    float rx = 0.f, ry = 0.f, rz = 0.f, rw = 0.f;
    for (int r = r0 + rh; r < rend; r += 8) {
        ushort4 v = *(const ushort4*)&Yb[(size_t)r * HDIM + c4 * 4];
        float x0 = bf2f(v.x), x1 = bf2f(v.y), x2 = bf2f(v.z), x3 = bf2f(v.w);
        sx += x0; sy += x1; sz += x2; sw += x3;
        qx = fmaf(x0, x0, qx); qy = fmaf(x1, x1, qy);
        qz = fmaf(x2, x2, qz); qw = fmaf(x3, x3, qw);
        int g = sseg[r - r0];
        if (g != curg) {
            if (curg >= 0) {
                float* pp = &pooled[curg * HDIM + c4 * 4];
                atomicAdd(pp + 0, rx); atomicAdd(pp + 1, ry);
                atomicAdd(pp + 2, rz); atomicAdd(pp + 3, rw);
            }
            curg = g;
            rx = x0; ry = x1; rz = x2; rw = x3;
        } else {
            rx += x0; ry += x1; rz += x2; rw += x3;
        }
    }
    if (curg >= 0) {
        float* pp = &pooled[curg * HDIM + c4 * 4];
        atomicAdd(pp + 0, rx); atomicAdd(pp + 1, ry);
        atomicAdd(pp + 2, rz); atomicAdd(pp + 3, rw);
    }
    red[t] = make_float4(sx, sy, sz, sw);
    __syncthreads();
    if (rh == 0) {
        float4 tot = red[c4];
        #pragma unroll
        for (int i = 1; i < 8; ++i) {
            float4 o = red[i * 32 + c4];
            tot.x += o.x; tot.y += o.y; tot.z += o.z; tot.w += o.w;
        }
        float* sp = &sums[c4 * 4];
        atomicAdd(sp + 0, tot.x); atomicAdd(sp + 1, tot.y);
        atomicAdd(sp + 2, tot.z); atomicAdd(sp + 3, tot.w);
    }
    __syncthreads();
    red[t] = make_float4(qx, qy, qz, qw);
    __syncthreads();
    if (rh == 0) {
        float4 tot = red[c4];
        #pragma unroll
        for (int i = 1; i < 8; ++i) {
            float4 o = red[i * 32 + c4];
            tot.x += o.x; tot.y += o.y; tot.z += o.z; tot.w += o.w;
        }
        float* sp = &sumsq[c4 * 4];
        atomicAdd(sp + 0, tot.x); atomicAdd(sp + 1, tot.y);
        atomicAdd(sp + 2, tot.z); atomicAdd(sp + 3, tot.w);
    }
}

// ---------------- per-layer head: BN finalize (local) + pooled head (+final MLP) ----------------
__global__ __launch_bounds__(256) void k_pool_head(const float* __restrict__ sums,
                                                   const float* __restrict__ sumsq,
                                                   const float* __restrict__ bng,
                                                   const float* __restrict__ bnb,
                                                   const float* __restrict__ pooled,
                                                   const int* __restrict__ gs,
                                                   const float* __restrict__ lw,
                                                   const float* __restrict__ lb,
                                                   const float* __restrict__ lg,
                                                   const float* __restrict__ lbt,
                                                   float* __restrict__ pbn,
                                                   int final_head,
                                                   const float* __restrict__ pbn_all,
                                                   const float* __restrict__ mw1,
                                                   const float* __restrict__ mg,
                                                   const float* __restrict__ mb,
                                                   const float* __restrict__ mw2,
                                                   float* __restrict__ out) {
    __shared__ float sA[HDIM], sB[HDIM];
    __shared__ float pl[G_GRAPHS][HID];
    __shared__ float hm[G_GRAPHS][HID];
    __shared__ float sc[HID], sh[HID];
    __shared__ float lgt[G_GRAPHS][NCLS];
    int t = threadIdx.x;
    if (t < HDIM) {
        float mu = sums[t] * (1.f / N_NODES);
        float var = fmaxf(sumsq[t] * (1.f / N_NODES) - mu * mu, 0.f);
        float inv = rsqrtf(var + BN_EPS);
        float a = bng[t] * inv;
        sA[t] = a;
        sB[t] = bnb[t] - a * mu;
    }
    __syncthreads();
    // pooled head: BN(pool) -> linear -> relu
    #pragma unroll
    for (int i = 0; i < (G_GRAPHS * HID) / 256; ++i) {  // 8
        int o = t + 256 * i;
        int row = o >> 5, col = o & 31;
        float cnt = (float)(gs[row + 1] - gs[row]);
        float acc = lb[col];
        for (int k = 0; k < HDIM; ++k) {
            float pin = fmaf(sA[k], pooled[row * HDIM + k], cnt * sB[k]);
            acc = fmaf(pin, lw[k * HID + col], acc);
        }
        pl[row][col] = fmaxf(acc, 0.f);
    }
    __syncthreads();
    if (t < HID) {
        float s = 0.f, q = 0.f;
        for (int r = 0; r < G_GRAPHS; ++r) {
            float v = pl[r][t];
            s += v; q = fmaf(v, v, q);
        }
        float mu = s * (1.f / G_GRAPHS);
        float var = fmaxf(q * (1.f / G_GRAPHS) - mu * mu, 0.f);
        float inv = rsqrtf(var + BN_EPS);
        float a = lg[t] * inv;
        sc[t] = a;
        sh[t] = lbt[t] - a * mu;
    }
    __syncthreads();
    #pragma unroll
    for (int i = 0; i < 8; ++i) {
        int o = t + 256 * i;
        int row = o >> 5, col = o & 31;
        float v = fmaf(pl[row][col], sc[col], sh[col]);
        pbn[o] = v;
        pl[row][col] = v;  // keep post-BN local for the fused final head
    }
    if (!final_head) return;

    // ---------------- final MLP head + log_softmax (layer 2 only) ----------------
    __syncthreads();
    #pragma unroll
    for (int i = 0; i < 8; ++i) {
        int o = t + 256 * i;
        int row = o >> 5, col = o & 31;
        float acc = 0.f;
        for (int kb = 0; kb < 2; ++kb)
            for (int k = 0; k < HID; ++k)
                acc = fmaf(pbn_all[kb * G_GRAPHS * HID + row * HID + k],
                           mw1[(kb * HID + k) * HID + col], acc);
        for (int k = 0; k < HID; ++k)
            acc = fmaf(pl[row][k], mw1[(2 * HID + k) * HID + col], acc);
        hm[row][col] = acc;
    }
    __syncthreads();
    if (t < HID) {
        float s = 0.f, q = 0.f;
        for (int r = 0; r < G_GRAPHS; ++r) {
            float v = hm[r][t];
            s += v; q = fmaf(v, v, q);
        }
        float mu = s * (1.f / G_GRAPHS);
        float var = fmaxf(q * (1.f / G_GRAPHS) - mu * mu, 0.f);
        float inv = rsqrtf(var + BN_EPS);
        float a = mg[t] * inv;
        sc[t] = a;
        sh[t] = mb[t] - a * mu;
    }
    __syncthreads();
    #pragma unroll
    for (int i = 0; i < 8; ++i) {
        int o = t + 256 * i;
        int row = o >> 5, col = o & 31;
        hm[row][col] = fmaxf(fmaf(hm[row][col], sc[col], sh[col]), 0.f);
    }
    __syncthreads();
    #pragma unroll
    for (int i = 0; i < 3; ++i) {
        int o = t + 256 * i;
        if (o < G_GRAPHS * NCLS) {
            int row = o / NCLS, col = o % NCLS;
            float acc = 0.f;
            for (int k = 0; k < HID; ++k) acc = fmaf(hm[row][k], mw2[k * NCLS + col], acc);
            lgt[row][col] = acc;
        }
    }
    __syncthreads();
    if (t < G_GRAPHS) {
        float mx = -INFINITY;
        for (int c = 0; c < NCLS; ++c) mx = fmaxf(mx, lgt[t][c]);
        float s = 0.f;
        for (int c = 0; c < NCLS; ++c) s += expf(lgt[t][c] - mx);
        float lse = mx + logf(s);
        for (int c = 0; c < NCLS; ++c) out[t * NCLS + c] = lgt[t][c] - lse;
    }
}

extern "C" void kernel_launch(void* const* d_in, const int* in_sizes, int n_in,
                              void* d_out, int out_size, void* d_ws, size_t ws_size,
                              hipStream_t stream) {
    (void)in_sizes; (void)n_in; (void)out_size; (void)ws_size;
    const float* feat = (const float*)d_in[0];
    const int* src = (const int*)d_in[1];
    const int* dst = (const int*)d_in[2];
    const int* seg = (const int*)d_in[3];
    auto LP = [&](int l, int j) { return (const float*)d_in[4 + 10 * l + j]; };
    const float* mw1 = (const float*)d_in[34];
    const float* mg  = (const float*)d_in[35];
    const float* mb  = (const float*)d_in[36];
    const float* mw2 = (const float*)d_in[37];

    char* p = (char*)d_ws;
    auto alloc = [&](size_t bytes) { char* r = p; p += (bytes + 255) & ~(size_t)255; return r; };
    unsigned short* Hb = (unsigned short*)alloc((size_t)N_NODES * HDIM * 2);
    unsigned short* Yb = (unsigned short*)alloc((size_t)N_NODES * HDIM * 2);
    int*   ssrc   = (int*)alloc((size_t)N_EDGES * 4);
    int*   rp     = (int*)alloc((size_t)(N_NODES + 1) * 4);
    int*   cursor = (int*)alloc((size_t)N_NODES * 4);
    int*   deg    = (int*)alloc((size_t)N_NODES * 4);
    float* statsAll = (float*)alloc((size_t)3 * STATS_STRIDE * 4);  // adjacent to deg: one memset
    float* pbn    = (float*)alloc((size_t)3 * G_GRAPHS * HID * 4);
    int*   gs     = (int*)alloc((size_t)(G_GRAPHS + 1) * 4);
    int*   bsum   = (int*)alloc((size_t)NB_SCAN * 4);
    unsigned short* WL = (unsigned short*)alloc((size_t)3 * HDIM * HDIM * 2);
    float* Fb     = (float*)alloc((size_t)3 * HDIM * 4);  // folded biases (layers 1,2)

    // zero deg + all per-layer stats in one shot (adjacent in ws)
    size_t zspan = (size_t)((char*)(statsAll + 3 * STATS_STRIDE) - (char*)deg);
    hipMemsetAsync(deg, 0, zspan, stream);

    // CSR build + layer-0 W prep
    k_prep_w<<<16, 256, 0, stream>>>(LP(0, 0), WL);
    k_count_deg<<<(N_EDGES + 255) / 256, 256, 0, stream>>>(dst, deg);
    k_blocksum<<<NB_SCAN + 1, 256, 0, stream>>>(deg, bsum, seg, gs);
    k_rowptr<<<NB_SCAN, 256, 0, stream>>>(deg, bsum, rp, cursor);
    k_fill<<<(N_EDGES + 255) / 256, 256, 0, stream>>>(src, dst, cursor, ssrc);

    const void* x = feat;
    for (int l = 0; l < 3; ++l) {
        float* sums   = statsAll + (size_t)l * STATS_STRIDE;
        float* sumsq  = sums + 128;
        float* pooled = sums + 256;
        const float* bias = l == 0 ? LP(0, 1) : Fb + (size_t)l * HDIM;
        if (l == 0)
            k_gemm_mfma<true><<<(N_NODES + 63) / 64, 256, 0, stream>>>(x, WL, bias, Hb);
        else
            k_gemm_mfma<false><<<(N_NODES + 63) / 64, 256, 0, stream>>>(
                x, WL + (size_t)l * HDIM * HDIM, bias, Hb);
        k_edge<<<(N_NODES + 3) / 4, 256, 0, stream>>>(Hb, rp, ssrc, LP(l, 2), LP(l, 3), Yb);
        k_stats_pool<<<NB_SCAN, 256, 0, stream>>>(Yb, seg, sums, sumsq, pooled);
        if (l < 2)
            k_fold_w<<<65, 256, 0, stream>>>(sums, sumsq, LP(l, 4), LP(l, 5),
                                             LP(l + 1, 0), LP(l + 1, 1),
                                             WL + (size_t)(l + 1) * HDIM * HDIM,
                                             Fb + (size_t)(l + 1) * HDIM);
        int isLast = (l == 2);
        k_pool_head<<<1, 256, 0, stream>>>(
            sums, sumsq, LP(l, 4), LP(l, 5), pooled, gs,
            LP(l, 6), LP(l, 7), LP(l, 8), LP(l, 9),
            pbn + (size_t)l * G_GRAPHS * HID,
            isLast, pbn, mw1, mg, mb, mw2, (float*)d_out);
        x = Yb;
    }
}

// Round 7
// 416.459 us; speedup vs baseline: 2.8137x; 1.1348x over previous
//
#include <hip/hip_runtime.h>
#include <math.h>

#define N_NODES 50000
#define N_EDGES 800000
#define G_GRAPHS 64
#define HDIM 128
#define HID 32
#define NCLS 10
#define BN_EPS 1e-5f
#define SLOPE 0.2f
#define NB_SCAN 196
#define STATS_STRIDE (256 + G_GRAPHS * HDIM)
#define DEFER_THR 8.0f

// bucket sort geometry
#define NBUCK 64
#define NPB 782              // nodes per bucket; 64*782 = 50048 >= N_NODES
#define CH 4096              // edges per scatter chunk
#define NCHUNK 196           // ceil(N_EDGES / CH)
#define NGB_GEMM 782         // gemm blocks: ceil(N_NODES/64)
#define CAP_OUT 13824        // per-bucket sort capacity (mean 12512, sigma 111 -> +11.8 sigma)

typedef __attribute__((ext_vector_type(8))) short bf16x8;
typedef __attribute__((ext_vector_type(4))) float f32x4;

__device__ __forceinline__ float lrelu(float x) { return fmaxf(x, SLOPE * x); }

__device__ __forceinline__ unsigned short f2bf(float x) {
    unsigned int u = __float_as_uint(x);
    u = (u + 0x7fffu + ((u >> 16) & 1u)) >> 16;
    return (unsigned short)u;
}
__device__ __forceinline__ unsigned int pk2bf(float lo, float hi) {
    unsigned int r;
    asm("v_cvt_pk_bf16_f32 %0, %1, %2" : "=v"(r) : "v"(lo), "v"(hi));
    return r;
}
__device__ __forceinline__ float2 up2(unsigned int u) {
    return make_float2(__uint_as_float(u << 16), __uint_as_float(u & 0xffff0000u));
}
__device__ __forceinline__ float bf2f(unsigned short u) {
    return __uint_as_float((unsigned int)u << 16);
}
__device__ __forceinline__ int wl_index(int k, int c) {
    int lane = ((k >> 3) & 3) * 16 + (c & 15);
    return (((k >> 5) * 8 + (c >> 4)) * 64 + lane) * 8 + (k & 7);
}

// ---------------- MFMA GEMM body: Hb = bf16( X @ W' + fb' ) ----------------
template <bool XF32>
__device__ __forceinline__ void gemm_body(int bid, const void* __restrict__ Xv,
                                          const unsigned short* __restrict__ WL,
                                          const float* __restrict__ fb,
                                          unsigned short* __restrict__ Hb) {
    int t = threadIdx.x;
    int w = t >> 6, lane = t & 63;
    int i16 = lane & 15, kg = lane >> 4;
    int r0w = bid * 64 + w * 16;
    int row = r0w + i16;
    int rowc = row < N_NODES ? row : N_NODES - 1;

    f32x4 acc[8];
    #pragma unroll
    for (int cs = 0; cs < 8; ++cs) acc[cs] = (f32x4){0.f, 0.f, 0.f, 0.f};

    #pragma unroll
    for (int ks = 0; ks < 4; ++ks) {
        union { uint4 u; bf16x8 s; } af;
        if (XF32) {
            const float* xp = (const float*)Xv + (size_t)rowc * HDIM + ks * 32 + kg * 8;
            float4 v0 = *(const float4*)xp;
            float4 v1 = *(const float4*)(xp + 4);
            af.u.x = pk2bf(v0.x, v0.y);
            af.u.y = pk2bf(v0.z, v0.w);
            af.u.z = pk2bf(v1.x, v1.y);
            af.u.w = pk2bf(v1.z, v1.w);
        } else {
            const unsigned short* xp = (const unsigned short*)Xv + (size_t)rowc * HDIM + ks * 32 + kg * 8;
            af.u = *(const uint4*)xp;
        }
        #pragma unroll
        for (int cs = 0; cs < 8; ++cs) {
            union { uint4 u; bf16x8 s; } bw;
            bw.u = *(const uint4*)&WL[(((ks << 3) + cs) * 64 + lane) * 8];
            acc[cs] = __builtin_amdgcn_mfma_f32_16x16x32_bf16(af.s, bw.s, acc[cs], 0, 0, 0);
        }
    }
    #pragma unroll
    for (int cs = 0; cs < 8; ++cs) {
        int col = cs * 16 + i16;
        float bias = fb[col];
        #pragma unroll
        for (int p = 0; p < 4; ++p) {
            int r = r0w + kg * 4 + p;
            if (r < N_NODES) Hb[(size_t)r * HDIM + col] = f2bf(acc[cs][p] + bias);
        }
    }
}

template <bool XF32>
__global__ __launch_bounds__(256) void k_gemm_mfma(const void* __restrict__ Xv,
                                                   const unsigned short* __restrict__ WL,
                                                   const float* __restrict__ fb,
                                                   unsigned short* __restrict__ Hb) {
    gemm_body<XF32>(blockIdx.x, Xv, WL, fb, Hb);
}

// ---------------- layer-0 W prep: MUST complete before k_mega0's gemm reads WL0 ----------------
__global__ __launch_bounds__(256) void k_prep_w(const float* __restrict__ W,
                                                unsigned short* __restrict__ WL) {
    for (int idx = blockIdx.x * 256 + threadIdx.x; idx < HDIM * HDIM; idx += 16 * 256) {
        int k = idx >> 7, c = idx & 127;
        WL[wl_index(k, c)] = f2bf(W[idx]);
    }
}

// ---------------- mega0: bucket histogram (196) + gemm L0 (782); WL0 written by prior dispatch ----------------
__global__ __launch_bounds__(256) void k_mega0(const int* __restrict__ dst,
                                               int* __restrict__ bcnt,
                                               const unsigned short* __restrict__ WL0,
                                               const float* __restrict__ feat,
                                               const float* __restrict__ fb0,
                                               unsigned short* __restrict__ Hb) {
    __shared__ unsigned int h[NBUCK];
    int bid = blockIdx.x;
    int t = threadIdx.x;
    if (bid < NCHUNK) {
        if (t < NBUCK) h[t] = 0;
        __syncthreads();
        int base = bid * CH;
        #pragma unroll
        for (int e = 0; e < 16; ++e) {
            int i = base + e * 256 + t;
            if (i < N_EDGES) {
                int d = dst[i];
                atomicAdd(&h[d / NPB], 1u);
            }
        }
        __syncthreads();
        if (t < NBUCK && h[t]) atomicAdd(&bcnt[t], (int)h[t]);
    } else {
        gemm_body<true>(bid - NCHUNK, feat, WL0, fb0, Hb);
    }
}

// ---------------- bucket scan (thread 255) + graph bounds (threads 0..64) ----------------
__global__ __launch_bounds__(256) void k_bscan(const int* __restrict__ bcnt,
                                               int* __restrict__ bbase,
                                               int* __restrict__ bcur,
                                               const int* __restrict__ seg,
                                               int* __restrict__ gs) {
    int t = threadIdx.x;
    if (t <= G_GRAPHS) {
        int g = t;
        int lo = 0, hi = N_NODES;
        while (lo < hi) {
            int mid = (lo + hi) >> 1;
            if (seg[mid] < g) lo = mid + 1; else hi = mid;
        }
        gs[g] = lo;
    }
    if (t == 255) {
        int run = 0;
        for (int b = 0; b < NBUCK; ++b) {
            bbase[b] = run;
            bcur[b] = run;
            run += bcnt[b];
        }
        bbase[NBUCK] = run;
    }
}

// ---------------- scatter into buckets (LDS chunk sort, coalesced runs) ----------------
__global__ __launch_bounds__(256) void k_bscatter(const int* __restrict__ dst,
                                                  const int* __restrict__ src,
                                                  int* __restrict__ bcur,
                                                  unsigned int* __restrict__ gbuf) {
    __shared__ unsigned int hist[NBUCK];
    __shared__ unsigned int scanB[NBUCK + 1];
    __shared__ int gdelta[NBUCK];
    __shared__ unsigned int cur[NBUCK];
    __shared__ unsigned int ent[CH];
    int t = threadIdx.x;
    int base = blockIdx.x * CH;
    unsigned int eb[16], een[16];
    if (t < NBUCK) hist[t] = 0;
    __syncthreads();
    #pragma unroll
    for (int e = 0; e < 16; ++e) {
        int i = base + e * 256 + t;
        if (i < N_EDGES) {
            int d = dst[i];
            int s = src[i];
            int b = d / NPB;
            eb[e] = (unsigned int)b;
            een[e] = ((unsigned int)(d - b * NPB) << 17) | (unsigned int)s;
            atomicAdd(&hist[b], 1u);
        } else {
            eb[e] = 0xFFFFFFFFu;
            een[e] = 0;
        }
    }
    __syncthreads();
    if (t < NBUCK) {
        unsigned int v = hist[t];
        unsigned int inc = v;
        #pragma unroll
        for (int off = 1; off < 64; off <<= 1) {
            unsigned int u = __shfl_up(inc, off);
            if ((t & 63) >= off) inc += u;
        }
        scanB[t + 1] = inc;
        if (t == 0) scanB[0] = 0;
    }
    __syncthreads();
    if (t < NBUCK) {
        unsigned int hv = hist[t];
        int gb = hv ? atomicAdd(&bcur[t], (int)hv) : 0;
        gdelta[t] = gb - (int)scanB[t];
        cur[t] = 0;
    }
    __syncthreads();
    #pragma unroll
    for (int e = 0; e < 16; ++e) {
        if (eb[e] < NBUCK) {
            unsigned int pos = scanB[eb[e]] + atomicAdd(&cur[eb[e]], 1u);
            ent[pos] = een[e];
        }
    }
    __syncthreads();
    unsigned int cntE = scanB[NBUCK];
    #pragma unroll
    for (int e = 0; e < 16; ++e) {
        unsigned int i = (unsigned int)(e * 256 + t);
        if (i < cntE) {
            int lo2 = 0, hi2 = NBUCK;
            while (hi2 - lo2 > 1) {
                int mid = (lo2 + hi2) >> 1;
                if (scanB[mid] <= i) lo2 = mid; else hi2 = mid;
            }
            gbuf[gdelta[lo2] + i] = ent[i];
        }
    }
}

// ---------------- per-bucket counting sort -> ssrc + rowptr (coalesced writes) ----------------
__global__ __launch_bounds__(256) void k_bsort(const int* __restrict__ bbase,
                                               const unsigned int* __restrict__ gbuf,
                                               int* __restrict__ ssrc,
                                               int* __restrict__ rowptr) {
    extern __shared__ unsigned int sout[];   // CAP_OUT
    __shared__ unsigned int hist[NPB];
    __shared__ unsigned int sbase[NPB + 1];
    __shared__ unsigned int cur[NPB];
    __shared__ unsigned int wsum[4];
    int b = blockIdx.x;
    int t = threadIdx.x;
    int lo = bbase[b], hi = bbase[b + 1];
    int cnt = hi - lo;
    if (cnt > CAP_OUT) cnt = CAP_OUT;  // safety clamp (statistically impossible)
    for (int i = t; i < NPB; i += 256) { hist[i] = 0; cur[i] = 0; }
    __syncthreads();
    for (int i = t; i < cnt; i += 256) {
        unsigned int e = gbuf[lo + i];
        atomicAdd(&hist[e >> 17], 1u);
    }
    __syncthreads();
    // block exclusive scan over NPB bins (4 bins/thread)
    unsigned int loc[4], s = 0;
    #pragma unroll
    for (int j = 0; j < 4; ++j) {
        int idx = t * 4 + j;
        loc[j] = idx < NPB ? hist[idx] : 0;
        s += loc[j];
    }
    unsigned int inc = s;
    #pragma unroll
    for (int off = 1; off < 64; off <<= 1) {
        unsigned int u = __shfl_up(inc, off);
        if ((t & 63) >= off) inc += u;
    }
    int wid = t >> 6;
    if ((t & 63) == 63) wsum[wid] = inc;
    __syncthreads();
    if (t == 0) {
        unsigned int r = 0;
        #pragma unroll
        for (int w = 0; w < 4; ++w) { unsigned int x = wsum[w]; wsum[w] = r; r += x; }
    }
    __syncthreads();
    unsigned int excl = inc - s + wsum[wid];
    #pragma unroll
    for (int j = 0; j < 4; ++j) {
        int idx = t * 4 + j;
        if (idx < NPB) { sbase[idx] = excl; excl += loc[j]; }
    }
    if (t == 255) sbase[NPB] = excl;
    __syncthreads();
    // rowptr
    for (int v = t; v < NPB; v += 256) {
        int nid = b * NPB + v;
        if (nid < N_NODES) rowptr[nid] = lo + (int)sbase[v];
    }
    if (b == NBUCK - 1 && t == 0) rowptr[N_NODES] = N_EDGES;
    // place into sorted LDS, then coalesced store
    for (int i = t; i < cnt; i += 256) {
        unsigned int e = gbuf[lo + i];
        unsigned int dl = e >> 17;
        unsigned int pos = sbase[dl] + atomicAdd(&cur[dl], 1u);
        if (pos < (unsigned int)CAP_OUT) sout[pos] = e & 0x1FFFFu;
    }
    __syncthreads();
    for (int i = t; i < cnt; i += 256) ssrc[lo + i] = (int)sout[i];
}

// ---------------- fused edge kernel: 4 edge-slots/wave, dwordx4 gathers ----------------
__global__ __launch_bounds__(256) void k_edge(const unsigned short* __restrict__ Hb,
                                              const int* __restrict__ row_ptr,
                                              const int* __restrict__ ssrc,
                                              const float* __restrict__ attn,
                                              const float* __restrict__ ob,
                                              unsigned short* __restrict__ Yb) {
    int wid = blockIdx.x * 4 + (threadIdx.x >> 6);
    if (wid >= N_NODES) return;
    int lane = threadIdx.x & 63;
    int slot = lane >> 4, s16 = lane & 15;
    int d0 = s16 << 3;
    int beg = row_ptr[wid], end = row_ptr[wid + 1];
    int deg = end - beg;
    if (deg == 0) {
        if (slot == 0) {
            float4 o0 = *(const float4*)&ob[d0];
            float4 o1 = *(const float4*)&ob[d0 + 4];
            uint4 w;
            w.x = pk2bf(fmaxf(o0.x, 0.f), fmaxf(o0.y, 0.f));
            w.y = pk2bf(fmaxf(o0.z, 0.f), fmaxf(o0.w, 0.f));
            w.z = pk2bf(fmaxf(o1.x, 0.f), fmaxf(o1.y, 0.f));
            w.w = pk2bf(fmaxf(o1.z, 0.f), fmaxf(o1.w, 0.f));
            *(uint4*)&Yb[(size_t)wid * HDIM + d0] = w;
        }
        return;
    }
    float er[8], at[8];
    {
        uint4 e = *(const uint4*)&Hb[(size_t)wid * HDIM + d0];
        unsigned int uu[4] = {e.x, e.y, e.z, e.w};
        #pragma unroll
        for (int i = 0; i < 4; ++i) {
            float2 f = up2(uu[i]);
            er[2 * i] = f.x; er[2 * i + 1] = f.y;
        }
        float4 a0 = *(const float4*)&attn[d0];
        float4 a1 = *(const float4*)&attn[d0 + 4];
        at[0] = a0.x; at[1] = a0.y; at[2] = a0.z; at[3] = a0.w;
        at[4] = a1.x; at[5] = a1.y; at[6] = a1.z; at[7] = a1.w;
    }
    const float NINF = __int_as_float(0xff800000);
    float m = -1e30f, den = 0.f;
    float acc[8] = {0.f, 0.f, 0.f, 0.f, 0.f, 0.f, 0.f, 0.f};
    int nit = (deg + 3) >> 2;
    int j = beg + slot;
    int sa;
    uint4 elc;
    {
        int jc0 = j < end ? j : beg;
        int jc1 = (j + 4) < end ? (j + 4) : beg;
        int s0 = ssrc[jc0];
        sa = ssrc[jc1];
        elc = *(const uint4*)&Hb[(size_t)s0 * HDIM + d0];
    }
    for (int it = 0; it < nit; ++it) {
        int j2 = j + 8;
        int jc2 = j2 < end ? j2 : beg;
        int sb = ssrc[jc2];
        uint4 eln = *(const uint4*)&Hb[(size_t)sa * HDIM + d0];
        bool act = j < end;
        float el[8];
        {
            unsigned int uu[4] = {elc.x, elc.y, elc.z, elc.w};
            #pragma unroll
            for (int i = 0; i < 4; ++i) {
                float2 f = up2(uu[i]);
                el[2 * i] = f.x; el[2 * i + 1] = f.y;
            }
        }
        float p = 0.f;
        #pragma unroll
        for (int d = 0; d < 8; ++d) p = fmaf(lrelu(el[d] + er[d]), at[d], p);
        p += __shfl_xor(p, 1);
        p += __shfl_xor(p, 2);
        float e = act ? p : NINF;
        if (__all(e - m <= DEFER_THR)) {
            float q = __expf(e - m);
            den += q;
            #pragma unroll
            for (int d = 0; d < 8; ++d) acc[d] = fmaf(el[d], q, acc[d]);
        } else {
            float nm = fmaxf(m, e);
            float r = __expf(m - nm);
            float q = __expf(e - nm);
            den = fmaf(den, r, q);
            #pragma unroll
            for (int d = 0; d < 8; ++d) acc[d] = fmaf(acc[d], r, el[d] * q);
            m = nm;
        }
        elc = eln; sa = sb; j += 4;
    }
    #pragma unroll
    for (int st = 16; st <= 32; st <<= 1) {
        float m2 = __shfl_xor(m, st);
        float den2 = __shfl_xor(den, st);
        float nm = fmaxf(m, m2);
        float r1 = __expf(m - nm);
        float r2 = __expf(m2 - nm);
        den = den * r1 + den2 * r2;
        #pragma unroll
        for (int d = 0; d < 8; ++d) {
            float a2 = __shfl_xor(acc[d], st);
            acc[d] = acc[d] * r1 + a2 * r2;
        }
        m = nm;
    }
    if (slot == 0) {
        float inv = den > 0.f ? 1.f / den : 0.f;
        float4 o0 = *(const float4*)&ob[d0];
        float4 o1 = *(const float4*)&ob[d0 + 4];
        float o[8] = {o0.x, o0.y, o0.z, o0.w, o1.x, o1.y, o1.z, o1.w};
        float r[8];
        #pragma unroll
        for (int d = 0; d < 8; ++d) r[d] = fmaxf(fmaf(acc[d], inv, o[d]), 0.f);
        uint4 w;
        w.x = pk2bf(r[0], r[1]);
        w.y = pk2bf(r[2], r[3]);
        w.z = pk2bf(r[4], r[5]);
        w.w = pk2bf(r[6], r[7]);
        *(uint4*)&Yb[(size_t)wid * HDIM + d0] = w;
    }
}

// ---------------- fused BN stats + per-graph sum pool ----------------
__global__ __launch_bounds__(256) void k_stats_pool(const unsigned short* __restrict__ Yb,
                                                    const int* __restrict__ seg,
                                                    float* __restrict__ sums,
                                                    float* __restrict__ sumsq,
                                                    float* __restrict__ pooled) {
    __shared__ float4 red[256];
    __shared__ int sseg[256];
    int t = threadIdx.x;
    int r0 = blockIdx.x * 256;
    if (r0 + t < N_NODES) sseg[t] = seg[r0 + t];
    __syncthreads();
    int c4 = t & 31, rh = t >> 5;
    int rend = r0 + 256 < N_NODES ? r0 + 256 : N_NODES;
    float sx = 0.f, sy = 0.f, sz = 0.f, sw = 0.f;
    float qx = 0.f, qy = 0.f, qz = 0.f, qw = 0.f;
    int curg = -1;
    float rx = 0.f, ry = 0.f, rz = 0.f, rw = 0.f;
    for (int r = r0 + rh; r < rend; r += 8) {
        ushort4 v = *(const ushort4*)&Yb[(size_t)r * HDIM + c4 * 4];
        float x0 = bf2f(v.x), x1 = bf2f(v.y), x2 = bf2f(v.z), x3 = bf2f(v.w);
        sx += x0; sy += x1; sz += x2; sw += x3;
        qx = fmaf(x0, x0, qx); qy = fmaf(x1, x1, qy);
        qz = fmaf(x2, x2, qz); qw = fmaf(x3, x3, qw);
        int g = sseg[r - r0];
        if (g != curg) {
            if (curg >= 0) {
                float* pp = &pooled[curg * HDIM + c4 * 4];
                atomicAdd(pp + 0, rx); atomicAdd(pp + 1, ry);
                atomicAdd(pp + 2, rz); atomicAdd(pp + 3, rw);
            }
            curg = g;
            rx = x0; ry = x1; rz = x2; rw = x3;
        } else {
            rx += x0; ry += x1; rz += x2; rw += x3;
        }
    }
    if (curg >= 0) {
        float* pp = &pooled[curg * HDIM + c4 * 4];
        atomicAdd(pp + 0, rx); atomicAdd(pp + 1, ry);
        atomicAdd(pp + 2, rz); atomicAdd(pp + 3, rw);
    }
    red[t] = make_float4(sx, sy, sz, sw);
    __syncthreads();
    if (rh == 0) {
        float4 tot = red[c4];
        #pragma unroll
        for (int i = 1; i < 8; ++i) {
            float4 o = red[i * 32 + c4];
            tot.x += o.x; tot.y += o.y; tot.z += o.z; tot.w += o.w;
        }
        float* sp = &sums[c4 * 4];
        atomicAdd(sp + 0, tot.x); atomicAdd(sp + 1, tot.y);
        atomicAdd(sp + 2, tot.z); atomicAdd(sp + 3, tot.w);
    }
    __syncthreads();
    red[t] = make_float4(qx, qy, qz, qw);
    __syncthreads();
    if (rh == 0) {
        float4 tot = red[c4];
        #pragma unroll
        for (int i = 1; i < 8; ++i) {
            float4 o = red[i * 32 + c4];
            tot.x += o.x; tot.y += o.y; tot.z += o.z; tot.w += o.w;
        }
        float* sp = &sumsq[c4 * 4];
        atomicAdd(sp + 0, tot.x); atomicAdd(sp + 1, tot.y);
        atomicAdd(sp + 2, tot.z); atomicAdd(sp + 3, tot.w);
    }
}

// ---------------- post: block0 = pool head (+final MLP); blocks 1..65 = W-fold ----------------
__global__ __launch_bounds__(256) void k_post(const float* __restrict__ sums,
                                              const float* __restrict__ sumsq,
                                              const float* __restrict__ bng,
                                              const float* __restrict__ bnb,
                                              const float* __restrict__ pooled,
                                              const int* __restrict__ gs,
                                              const float* __restrict__ lw,
                                              const float* __restrict__ lb,
                                              const float* __restrict__ lg,
                                              const float* __restrict__ lbt,
                                              float* __restrict__ pbn,
                                              int final_head,
                                              const float* __restrict__ pbn_all,
                                              const float* __restrict__ mw1,
                                              const float* __restrict__ mg,
                                              const float* __restrict__ mb,
                                              const float* __restrict__ mw2,
                                              float* __restrict__ out,
                                              const float* __restrict__ Wnext,
                                              const float* __restrict__ fbnext,
                                              unsigned short* __restrict__ WLnext,
                                              float* __restrict__ Fbnext) {
    __shared__ float sA[HDIM], sB[HDIM];
    __shared__ float pl[G_GRAPHS][HID];
    __shared__ float hm[G_GRAPHS][HID];
    __shared__ float sc[HID], sh[HID];
    __shared__ float lgt[G_GRAPHS][NCLS];
    int t = threadIdx.x;
    if (t < HDIM) {
        float mu = sums[t] * (1.f / N_NODES);
        float var = fmaxf(sumsq[t] * (1.f / N_NODES) - mu * mu, 0.f);
        float inv = rsqrtf(var + BN_EPS);
        float a = bng[t] * inv;
        sA[t] = a;
        sB[t] = bnb[t] - a * mu;
    }
    __syncthreads();
    if (blockIdx.x > 0) {
        int fbid = blockIdx.x - 1;
        if (fbid < 64) {
            int idx = fbid * 256 + t;
            int k = idx >> 7, c = idx & 127;
            WLnext[wl_index(k, c)] = f2bf(sA[k] * Wnext[idx]);
        } else if (t < HDIM) {
            float a = fbnext[t];
            for (int k = 0; k < HDIM; ++k) a = fmaf(sB[k], Wnext[k * HDIM + t], a);
            Fbnext[t] = a;
        }
        return;
    }
    // pooled head: BN(pool) -> linear -> relu
    #pragma unroll
    for (int i = 0; i < (G_GRAPHS * HID) / 256; ++i) {
        int o = t + 256 * i;
        int row = o >> 5, col = o & 31;
        float cnt = (float)(gs[row + 1] - gs[row]);
        float acc = lb[col];
        for (int k = 0; k < HDIM; ++k) {
            float pin = fmaf(sA[k], pooled[row * HDIM + k], cnt * sB[k]);
            acc = fmaf(pin, lw[k * HID + col], acc);
        }
        pl[row][col] = fmaxf(acc, 0.f);
    }
    __syncthreads();
    if (t < HID) {
        float s = 0.f, q = 0.f;
        for (int r = 0; r < G_GRAPHS; ++r) {
            float v = pl[r][t];
            s += v; q = fmaf(v, v, q);
        }
        float mu = s * (1.f / G_GRAPHS);
        float var = fmaxf(q * (1.f / G_GRAPHS) - mu * mu, 0.f);
        float inv = rsqrtf(var + BN_EPS);
        float a = lg[t] * inv;
        sc[t] = a;
        sh[t] = lbt[t] - a * mu;
    }
    __syncthreads();
    #pragma unroll
    for (int i = 0; i < 8; ++i) {
        int o = t + 256 * i;
        int row = o >> 5, col = o & 31;
        float v = fmaf(pl[row][col], sc[col], sh[col]);
        pbn[o] = v;
        pl[row][col] = v;
    }
    if (!final_head) return;

    __syncthreads();
    #pragma unroll
    for (int i = 0; i < 8; ++i) {
        int o = t + 256 * i;
        int row = o >> 5, col = o & 31;
        float acc = 0.f;
        for (int kb = 0; kb < 2; ++kb)
            for (int k = 0; k < HID; ++k)
                acc = fmaf(pbn_all[kb * G_GRAPHS * HID + row * HID + k],
                           mw1[(kb * HID + k) * HID + col], acc);
        for (int k = 0; k < HID; ++k)
            acc = fmaf(pl[row][k], mw1[(2 * HID + k) * HID + col], acc);
        hm[row][col] = acc;
    }
    __syncthreads();
    if (t < HID) {
        float s = 0.f, q = 0.f;
        for (int r = 0; r < G_GRAPHS; ++r) {
            float v = hm[r][t];
            s += v; q = fmaf(v, v, q);
        }
        float mu = s * (1.f / G_GRAPHS);
        float var = fmaxf(q * (1.f / G_GRAPHS) - mu * mu, 0.f);
        float inv = rsqrtf(var + BN_EPS);
        float a = mg[t] * inv;
        sc[t] = a;
        sh[t] = mb[t] - a * mu;
    }
    __syncthreads();
    #pragma unroll
    for (int i = 0; i < 8; ++i) {
        int o = t + 256 * i;
        int row = o >> 5, col = o & 31;
        hm[row][col] = fmaxf(fmaf(hm[row][col], sc[col], sh[col]), 0.f);
    }
    __syncthreads();
    #pragma unroll
    for (int i = 0; i < 3; ++i) {
        int o = t + 256 * i;
        if (o < G_GRAPHS * NCLS) {
            int row = o / NCLS, col = o % NCLS;
            float acc = 0.f;
            for (int k = 0; k < HID; ++k) acc = fmaf(hm[row][k], mw2[k * NCLS + col], acc);
            lgt[row][col] = acc;
        }
    }
    __syncthreads();
    if (t < G_GRAPHS) {
        float mx = -INFINITY;
        for (int c = 0; c < NCLS; ++c) mx = fmaxf(mx, lgt[t][c]);
        float s = 0.f;
        for (int c = 0; c < NCLS; ++c) s += expf(lgt[t][c] - mx);
        float lse = mx + logf(s);
        for (int c = 0; c < NCLS; ++c) out[t * NCLS + c] = lgt[t][c] - lse;
    }
}

extern "C" void kernel_launch(void* const* d_in, const int* in_sizes, int n_in,
                              void* d_out, int out_size, void* d_ws, size_t ws_size,
                              hipStream_t stream) {
    (void)in_sizes; (void)n_in; (void)out_size; (void)ws_size;
    const float* feat = (const float*)d_in[0];
    const int* src = (const int*)d_in[1];
    const int* dst = (const int*)d_in[2];
    const int* seg = (const int*)d_in[3];
    auto LP = [&](int l, int j) { return (const float*)d_in[4 + 10 * l + j]; };
    const float* mw1 = (const float*)d_in[34];
    const float* mg  = (const float*)d_in[35];
    const float* mb  = (const float*)d_in[36];
    const float* mw2 = (const float*)d_in[37];

    char* p = (char*)d_ws;
    auto alloc = [&](size_t bytes) { char* r = p; p += (bytes + 255) & ~(size_t)255; return r; };
    unsigned short* Hb = (unsigned short*)alloc((size_t)N_NODES * HDIM * 2);
    unsigned short* Yb = (unsigned short*)alloc((size_t)N_NODES * HDIM * 2);
    int*   ssrc   = (int*)alloc((size_t)N_EDGES * 4);
    unsigned int* gbuf = (unsigned int*)alloc((size_t)N_EDGES * 4);
    int*   rp     = (int*)alloc((size_t)(N_NODES + 1) * 4);
    int*   bcnt   = (int*)alloc((size_t)NBUCK * 4);       // zeroed (adjacent to statsAll)
    float* statsAll = (float*)alloc((size_t)3 * STATS_STRIDE * 4);
    int*   bbase  = (int*)alloc((size_t)(NBUCK + 1) * 4);
    int*   bcur   = (int*)alloc((size_t)NBUCK * 4);
    float* pbn    = (float*)alloc((size_t)3 * G_GRAPHS * HID * 4);
    int*   gs     = (int*)alloc((size_t)(G_GRAPHS + 1) * 4);
    unsigned short* WL = (unsigned short*)alloc((size_t)3 * HDIM * HDIM * 2);
    float* Fb     = (float*)alloc((size_t)3 * HDIM * 4);

    // zero bcnt + all per-layer stats (adjacent in ws)
    size_t zspan = (size_t)((char*)(statsAll + 3 * STATS_STRIDE) - (char*)bcnt);
    hipMemsetAsync(bcnt, 0, zspan, stream);

    // layer-0 W prep FIRST (k_mega0's gemm blocks read WL -> must be a prior dispatch)
    k_prep_w<<<16, 256, 0, stream>>>(LP(0, 0), WL);
    // bucket histogram + layer-0 GEMM, fused (independent inputs)
    k_mega0<<<NCHUNK + NGB_GEMM, 256, 0, stream>>>(dst, bcnt, WL, feat, LP(0, 1), Hb);
    k_bscan<<<1, 256, 0, stream>>>(bcnt, bbase, bcur, seg, gs);
    k_bscatter<<<NCHUNK, 256, 0, stream>>>(dst, src, bcur, gbuf);
    k_bsort<<<NBUCK, 256, CAP_OUT * 4, stream>>>(bbase, gbuf, ssrc, rp);

    for (int l = 0; l < 3; ++l) {
        float* sums   = statsAll + (size_t)l * STATS_STRIDE;
        float* sumsq  = sums + 128;
        float* pooled = sums + 256;
        if (l > 0) {
            k_gemm_mfma<false><<<NGB_GEMM, 256, 0, stream>>>(
                Yb, WL + (size_t)l * HDIM * HDIM, Fb + (size_t)l * HDIM, Hb);
        }
        k_edge<<<(N_NODES + 3) / 4, 256, 0, stream>>>(Hb, rp, ssrc, LP(l, 2), LP(l, 3), Yb);
        k_stats_pool<<<NB_SCAN, 256, 0, stream>>>(Yb, seg, sums, sumsq, pooled);
        int isLast = (l == 2);
        k_post<<<isLast ? 1 : 66, 256, 0, stream>>>(
            sums, sumsq, LP(l, 4), LP(l, 5), pooled, gs,
            LP(l, 6), LP(l, 7), LP(l, 8), LP(l, 9),
            pbn + (size_t)l * G_GRAPHS * HID,
            isLast, pbn, mw1, mg, mb, mw2, (float*)d_out,
            isLast ? nullptr : LP(l + 1, 0), isLast ? nullptr : LP(l + 1, 1),
            isLast ? nullptr : WL + (size_t)(l + 1) * HDIM * HDIM,
            isLast ? nullptr : Fb + (size_t)(l + 1) * HDIM);
    }
}

// Round 8
// 336.564 us; speedup vs baseline: 3.4816x; 1.2374x over previous
//
#include <hip/hip_runtime.h>
#include <math.h>

#define N_NODES 50000
#define N_EDGES 800000
#define G_GRAPHS 64
#define HDIM 128
#define HID 32
#define NCLS 10
#define BN_EPS 1e-5f
#define SLOPE 0.2f
#define NB_SCAN 196
#define STATS_STRIDE (256 + G_GRAPHS * HDIM)
#define DEFER_THR 8.0f

// bucket sort geometry
#define NBUCK 64
#define NPB 782              // nodes per bucket; 64*782 = 50048 >= N_NODES
#define CH 4096              // edges per scatter chunk
#define NCHUNK 196           // ceil(N_EDGES / CH)
#define NGB_GEMM 782         // gemm blocks: ceil(N_NODES/64)
#define CAP_OUT 13824        // per-bucket sort capacity (mean 12512, sigma 111)

typedef __attribute__((ext_vector_type(8))) short bf16x8;
typedef __attribute__((ext_vector_type(4))) float f32x4;

__device__ __forceinline__ float lrelu(float x) { return fmaxf(x, SLOPE * x); }

__device__ __forceinline__ unsigned short f2bf(float x) {
    unsigned int u = __float_as_uint(x);
    u = (u + 0x7fffu + ((u >> 16) & 1u)) >> 16;
    return (unsigned short)u;
}
__device__ __forceinline__ unsigned int pk2bf(float lo, float hi) {
    unsigned int r;
    asm("v_cvt_pk_bf16_f32 %0, %1, %2" : "=v"(r) : "v"(lo), "v"(hi));
    return r;
}
__device__ __forceinline__ float2 up2(unsigned int u) {
    return make_float2(__uint_as_float(u << 16), __uint_as_float(u & 0xffff0000u));
}
__device__ __forceinline__ float bf2f(unsigned short u) {
    return __uint_as_float((unsigned int)u << 16);
}
__device__ __forceinline__ int wl_index(int k, int c) {
    int lane = ((k >> 3) & 3) * 16 + (c & 15);
    return (((k >> 5) * 8 + (c >> 4)) * 64 + lane) * 8 + (k & 7);
}

// ---------------- MFMA GEMM body: Hb = bf16( X @ W' + fb' ) ----------------
template <bool XF32>
__device__ __forceinline__ void gemm_body(int bid, const void* __restrict__ Xv,
                                          const unsigned short* __restrict__ WL,
                                          const float* __restrict__ fb,
                                          unsigned short* __restrict__ Hb) {
    int t = threadIdx.x;
    int w = t >> 6, lane = t & 63;
    int i16 = lane & 15, kg = lane >> 4;
    int r0w = bid * 64 + w * 16;
    int row = r0w + i16;
    int rowc = row < N_NODES ? row : N_NODES - 1;

    f32x4 acc[8];
    #pragma unroll
    for (int cs = 0; cs < 8; ++cs) acc[cs] = (f32x4){0.f, 0.f, 0.f, 0.f};

    #pragma unroll
    for (int ks = 0; ks < 4; ++ks) {
        union { uint4 u; bf16x8 s; } af;
        if (XF32) {
            const float* xp = (const float*)Xv + (size_t)rowc * HDIM + ks * 32 + kg * 8;
            float4 v0 = *(const float4*)xp;
            float4 v1 = *(const float4*)(xp + 4);
            af.u.x = pk2bf(v0.x, v0.y);
            af.u.y = pk2bf(v0.z, v0.w);
            af.u.z = pk2bf(v1.x, v1.y);
            af.u.w = pk2bf(v1.z, v1.w);
        } else {
            const unsigned short* xp = (const unsigned short*)Xv + (size_t)rowc * HDIM + ks * 32 + kg * 8;
            af.u = *(const uint4*)xp;
        }
        #pragma unroll
        for (int cs = 0; cs < 8; ++cs) {
            union { uint4 u; bf16x8 s; } bw;
            bw.u = *(const uint4*)&WL[(((ks << 3) + cs) * 64 + lane) * 8];
            acc[cs] = __builtin_amdgcn_mfma_f32_16x16x32_bf16(af.s, bw.s, acc[cs], 0, 0, 0);
        }
    }
    #pragma unroll
    for (int cs = 0; cs < 8; ++cs) {
        int col = cs * 16 + i16;
        float bias = fb[col];
        #pragma unroll
        for (int p = 0; p < 4; ++p) {
            int r = r0w + kg * 4 + p;
            if (r < N_NODES) Hb[(size_t)r * HDIM + col] = f2bf(acc[cs][p] + bias);
        }
    }
}

template <bool XF32>
__global__ __launch_bounds__(256) void k_gemm_mfma(const void* __restrict__ Xv,
                                                   const unsigned short* __restrict__ WL,
                                                   const float* __restrict__ fb,
                                                   unsigned short* __restrict__ Hb) {
    gemm_body<XF32>(blockIdx.x, Xv, WL, fb, Hb);
}

// ---------------- layer-0 W prep (separate dispatch: k_mega0's gemm reads WL0) ----------------
__global__ __launch_bounds__(256) void k_prep_w(const float* __restrict__ W,
                                                unsigned short* __restrict__ WL) {
    for (int idx = blockIdx.x * 256 + threadIdx.x; idx < HDIM * HDIM; idx += 16 * 256) {
        int k = idx >> 7, c = idx & 127;
        WL[wl_index(k, c)] = f2bf(W[idx]);
    }
}

// ---------------- mega0: bucket histogram (196) + gemm L0 (782) ----------------
__global__ __launch_bounds__(256) void k_mega0(const int* __restrict__ dst,
                                               int* __restrict__ bcnt,
                                               const unsigned short* __restrict__ WL0,
                                               const float* __restrict__ feat,
                                               const float* __restrict__ fb0,
                                               unsigned short* __restrict__ Hb) {
    __shared__ unsigned int h[NBUCK];
    int bid = blockIdx.x;
    int t = threadIdx.x;
    if (bid < NCHUNK) {
        if (t < NBUCK) h[t] = 0;
        __syncthreads();
        int base = bid * CH;
        #pragma unroll
        for (int e = 0; e < 16; ++e) {
            int i = base + e * 256 + t;
            if (i < N_EDGES) {
                int d = dst[i];
                atomicAdd(&h[d / NPB], 1u);
            }
        }
        __syncthreads();
        if (t < NBUCK && h[t]) atomicAdd(&bcnt[t], (int)h[t]);
    } else {
        gemm_body<true>(bid - NCHUNK, feat, WL0, fb0, Hb);
    }
}

// ---------------- bucket scan (thread 255) + graph bounds (threads 0..64) ----------------
__global__ __launch_bounds__(256) void k_bscan(const int* __restrict__ bcnt,
                                               int* __restrict__ bbase,
                                               int* __restrict__ bcur,
                                               const int* __restrict__ seg,
                                               int* __restrict__ gs) {
    int t = threadIdx.x;
    if (t <= G_GRAPHS) {
        int g = t;
        int lo = 0, hi = N_NODES;
        while (lo < hi) {
            int mid = (lo + hi) >> 1;
            if (seg[mid] < g) lo = mid + 1; else hi = mid;
        }
        gs[g] = lo;
    }
    if (t == 255) {
        int run = 0;
        for (int b = 0; b < NBUCK; ++b) {
            bbase[b] = run;
            bcur[b] = run;
            run += bcnt[b];
        }
        bbase[NBUCK] = run;
    }
}

// ---------------- scatter into buckets (LDS chunk sort, coalesced runs) ----------------
__global__ __launch_bounds__(256) void k_bscatter(const int* __restrict__ dst,
                                                  const int* __restrict__ src,
                                                  int* __restrict__ bcur,
                                                  unsigned int* __restrict__ gbuf) {
    __shared__ unsigned int hist[NBUCK];
    __shared__ unsigned int scanB[NBUCK + 1];
    __shared__ int gdelta[NBUCK];
    __shared__ unsigned int cur[NBUCK];
    __shared__ unsigned int ent[CH];
    int t = threadIdx.x;
    int base = blockIdx.x * CH;
    unsigned int eb[16], een[16];
    if (t < NBUCK) hist[t] = 0;
    __syncthreads();
    #pragma unroll
    for (int e = 0; e < 16; ++e) {
        int i = base + e * 256 + t;
        if (i < N_EDGES) {
            int d = dst[i];
            int s = src[i];
            int b = d / NPB;
            eb[e] = (unsigned int)b;
            een[e] = ((unsigned int)(d - b * NPB) << 17) | (unsigned int)s;
            atomicAdd(&hist[b], 1u);
        } else {
            eb[e] = 0xFFFFFFFFu;
            een[e] = 0;
        }
    }
    __syncthreads();
    if (t < NBUCK) {
        unsigned int v = hist[t];
        unsigned int inc = v;
        #pragma unroll
        for (int off = 1; off < 64; off <<= 1) {
            unsigned int u = __shfl_up(inc, off);
            if ((t & 63) >= off) inc += u;
        }
        scanB[t + 1] = inc;
        if (t == 0) scanB[0] = 0;
    }
    __syncthreads();
    if (t < NBUCK) {
        unsigned int hv = hist[t];
        int gb = hv ? atomicAdd(&bcur[t], (int)hv) : 0;
        gdelta[t] = gb - (int)scanB[t];
        cur[t] = 0;
    }
    __syncthreads();
    #pragma unroll
    for (int e = 0; e < 16; ++e) {
        if (eb[e] < NBUCK) {
            unsigned int pos = scanB[eb[e]] + atomicAdd(&cur[eb[e]], 1u);
            ent[pos] = een[e];
        }
    }
    __syncthreads();
    unsigned int cntE = scanB[NBUCK];
    #pragma unroll
    for (int e = 0; e < 16; ++e) {
        unsigned int i = (unsigned int)(e * 256 + t);
        if (i < cntE) {
            int lo2 = 0, hi2 = NBUCK;
            while (hi2 - lo2 > 1) {
                int mid = (lo2 + hi2) >> 1;
                if (scanB[mid] <= i) lo2 = mid; else hi2 = mid;
            }
            gbuf[gdelta[lo2] + i] = ent[i];
        }
    }
}

// ---------------- per-bucket counting sort -> ssrc + rowptr ----------------
__global__ __launch_bounds__(256) void k_bsort(const int* __restrict__ bbase,
                                               const unsigned int* __restrict__ gbuf,
                                               int* __restrict__ ssrc,
                                               int* __restrict__ rowptr) {
    extern __shared__ unsigned int sout[];   // CAP_OUT
    __shared__ unsigned int hist[NPB];
    __shared__ unsigned int sbase[NPB + 1];
    __shared__ unsigned int cur[NPB];
    __shared__ unsigned int wsum[4];
    int b = blockIdx.x;
    int t = threadIdx.x;
    int lo = bbase[b], hi = bbase[b + 1];
    int cnt = hi - lo;
    if (cnt > CAP_OUT) cnt = CAP_OUT;
    for (int i = t; i < NPB; i += 256) { hist[i] = 0; cur[i] = 0; }
    __syncthreads();
    for (int i = t; i < cnt; i += 256) {
        unsigned int e = gbuf[lo + i];
        atomicAdd(&hist[e >> 17], 1u);
    }
    __syncthreads();
    unsigned int loc[4], s = 0;
    #pragma unroll
    for (int j = 0; j < 4; ++j) {
        int idx = t * 4 + j;
        loc[j] = idx < NPB ? hist[idx] : 0;
        s += loc[j];
    }
    unsigned int inc = s;
    #pragma unroll
    for (int off = 1; off < 64; off <<= 1) {
        unsigned int u = __shfl_up(inc, off);
        if ((t & 63) >= off) inc += u;
    }
    int wid = t >> 6;
    if ((t & 63) == 63) wsum[wid] = inc;
    __syncthreads();
    if (t == 0) {
        unsigned int r = 0;
        #pragma unroll
        for (int w = 0; w < 4; ++w) { unsigned int x = wsum[w]; wsum[w] = r; r += x; }
    }
    __syncthreads();
    unsigned int excl = inc - s + wsum[wid];
    #pragma unroll
    for (int j = 0; j < 4; ++j) {
        int idx = t * 4 + j;
        if (idx < NPB) { sbase[idx] = excl; excl += loc[j]; }
    }
    if (t == 255) sbase[NPB] = excl;
    __syncthreads();
    for (int v = t; v < NPB; v += 256) {
        int nid = b * NPB + v;
        if (nid < N_NODES) rowptr[nid] = lo + (int)sbase[v];
    }
    if (b == NBUCK - 1 && t == 0) rowptr[N_NODES] = N_EDGES;
    for (int i = t; i < cnt; i += 256) {
        unsigned int e = gbuf[lo + i];
        unsigned int dl = e >> 17;
        unsigned int pos = sbase[dl] + atomicAdd(&cur[dl], 1u);
        if (pos < (unsigned int)CAP_OUT) sout[pos] = e & 0x1FFFFu;
    }
    __syncthreads();
    for (int i = t; i < cnt; i += 256) ssrc[lo + i] = (int)sout[i];
}

// ---------------- fused edge kernel: 4 edge-slots/wave, dwordx4 gathers ----------------
__global__ __launch_bounds__(256) void k_edge(const unsigned short* __restrict__ Hb,
                                              const int* __restrict__ row_ptr,
                                              const int* __restrict__ ssrc,
                                              const float* __restrict__ attn,
                                              const float* __restrict__ ob,
                                              unsigned short* __restrict__ Yb) {
    int wid = blockIdx.x * 4 + (threadIdx.x >> 6);
    if (wid >= N_NODES) return;
    int lane = threadIdx.x & 63;
    int slot = lane >> 4, s16 = lane & 15;
    int d0 = s16 << 3;
    int beg = row_ptr[wid], end = row_ptr[wid + 1];
    int deg = end - beg;
    if (deg == 0) {
        if (slot == 0) {
            float4 o0 = *(const float4*)&ob[d0];
            float4 o1 = *(const float4*)&ob[d0 + 4];
            uint4 w;
            w.x = pk2bf(fmaxf(o0.x, 0.f), fmaxf(o0.y, 0.f));
            w.y = pk2bf(fmaxf(o0.z, 0.f), fmaxf(o0.w, 0.f));
            w.z = pk2bf(fmaxf(o1.x, 0.f), fmaxf(o1.y, 0.f));
            w.w = pk2bf(fmaxf(o1.z, 0.f), fmaxf(o1.w, 0.f));
            *(uint4*)&Yb[(size_t)wid * HDIM + d0] = w;
        }
        return;
    }
    float er[8], at[8];
    {
        uint4 e = *(const uint4*)&Hb[(size_t)wid * HDIM + d0];
        unsigned int uu[4] = {e.x, e.y, e.z, e.w};
        #pragma unroll
        for (int i = 0; i < 4; ++i) {
            float2 f = up2(uu[i]);
            er[2 * i] = f.x; er[2 * i + 1] = f.y;
        }
        float4 a0 = *(const float4*)&attn[d0];
        float4 a1 = *(const float4*)&attn[d0 + 4];
        at[0] = a0.x; at[1] = a0.y; at[2] = a0.z; at[3] = a0.w;
        at[4] = a1.x; at[5] = a1.y; at[6] = a1.z; at[7] = a1.w;
    }
    const float NINF = __int_as_float(0xff800000);
    float m = -1e30f, den = 0.f;
    float acc[8] = {0.f, 0.f, 0.f, 0.f, 0.f, 0.f, 0.f, 0.f};
    int nit = (deg + 3) >> 2;
    int j = beg + slot;
    int sa;
    uint4 elc;
    {
        int jc0 = j < end ? j : beg;
        int jc1 = (j + 4) < end ? (j + 4) : beg;
        int s0 = ssrc[jc0];
        sa = ssrc[jc1];
        elc = *(const uint4*)&Hb[(size_t)s0 * HDIM + d0];
    }
    for (int it = 0; it < nit; ++it) {
        int j2 = j + 8;
        int jc2 = j2 < end ? j2 : beg;
        int sb = ssrc[jc2];
        uint4 eln = *(const uint4*)&Hb[(size_t)sa * HDIM + d0];
        bool act = j < end;
        float el[8];
        {
            unsigned int uu[4] = {elc.x, elc.y, elc.z, elc.w};
            #pragma unroll
            for (int i = 0; i < 4; ++i) {
                float2 f = up2(uu[i]);
                el[2 * i] = f.x; el[2 * i + 1] = f.y;
            }
        }
        float p = 0.f;
        #pragma unroll
        for (int d = 0; d < 8; ++d) p = fmaf(lrelu(el[d] + er[d]), at[d], p);
        p += __shfl_xor(p, 1);
        p += __shfl_xor(p, 2);
        float e = act ? p : NINF;
        if (__all(e - m <= DEFER_THR)) {
            float q = __expf(e - m);
            den += q;
            #pragma unroll
            for (int d = 0; d < 8; ++d) acc[d] = fmaf(el[d], q, acc[d]);
        } else {
            float nm = fmaxf(m, e);
            float r = __expf(m - nm);
            float q = __expf(e - nm);
            den = fmaf(den, r, q);
            #pragma unroll
            for (int d = 0; d < 8; ++d) acc[d] = fmaf(acc[d], r, el[d] * q);
            m = nm;
        }
        elc = eln; sa = sb; j += 4;
    }
    #pragma unroll
    for (int st = 16; st <= 32; st <<= 1) {
        float m2 = __shfl_xor(m, st);
        float den2 = __shfl_xor(den, st);
        float nm = fmaxf(m, m2);
        float r1 = __expf(m - nm);
        float r2 = __expf(m2 - nm);
        den = den * r1 + den2 * r2;
        #pragma unroll
        for (int d = 0; d < 8; ++d) {
            float a2 = __shfl_xor(acc[d], st);
            acc[d] = acc[d] * r1 + a2 * r2;
        }
        m = nm;
    }
    if (slot == 0) {
        float inv = den > 0.f ? 1.f / den : 0.f;
        float4 o0 = *(const float4*)&ob[d0];
        float4 o1 = *(const float4*)&ob[d0 + 4];
        float o[8] = {o0.x, o0.y, o0.z, o0.w, o1.x, o1.y, o1.z, o1.w};
        float r[8];
        #pragma unroll
        for (int d = 0; d < 8; ++d) r[d] = fmaxf(fmaf(acc[d], inv, o[d]), 0.f);
        uint4 w;
        w.x = pk2bf(r[0], r[1]);
        w.y = pk2bf(r[2], r[3]);
        w.z = pk2bf(r[4], r[5]);
        w.w = pk2bf(r[6], r[7]);
        *(uint4*)&Yb[(size_t)wid * HDIM + d0] = w;
    }
}

// ---------------- fused BN stats + per-graph sum pool ----------------
__global__ __launch_bounds__(256) void k_stats_pool(const unsigned short* __restrict__ Yb,
                                                    const int* __restrict__ seg,
                                                    float* __restrict__ sums,
                                                    float* __restrict__ sumsq,
                                                    float* __restrict__ pooled) {
    __shared__ float4 red[256];
    __shared__ int sseg[256];
    int t = threadIdx.x;
    int r0 = blockIdx.x * 256;
    if (r0 + t < N_NODES) sseg[t] = seg[r0 + t];
    __syncthreads();
    int c4 = t & 31, rh = t >> 5;
    int rend = r0 + 256 < N_NODES ? r0 + 256 : N_NODES;
    float sx = 0.f, sy = 0.f, sz = 0.f, sw = 0.f;
    float qx = 0.f, qy = 0.f, qz = 0.f, qw = 0.f;
    int curg = -1;
    float rx = 0.f, ry = 0.f, rz = 0.f, rw = 0.f;
    for (int r = r0 + rh; r < rend; r += 8) {
        ushort4 v = *(const ushort4*)&Yb[(size_t)r * HDIM + c4 * 4];
        float x0 = bf2f(v.x), x1 = bf2f(v.y), x2 = bf2f(v.z), x3 = bf2f(v.w);
        sx += x0; sy += x1; sz += x2; sw += x3;
        qx = fmaf(x0, x0, qx); qy = fmaf(x1, x1, qy);
        qz = fmaf(x2, x2, qz); qw = fmaf(x3, x3, qw);
        int g = sseg[r - r0];
        if (g != curg) {
            if (curg >= 0) {
                float* pp = &pooled[curg * HDIM + c4 * 4];
                atomicAdd(pp + 0, rx); atomicAdd(pp + 1, ry);
                atomicAdd(pp + 2, rz); atomicAdd(pp + 3, rw);
            }
            curg = g;
            rx = x0; ry = x1; rz = x2; rw = x3;
        } else {
            rx += x0; ry += x1; rz += x2; rw += x3;
        }
    }
    if (curg >= 0) {
        float* pp = &pooled[curg * HDIM + c4 * 4];
        atomicAdd(pp + 0, rx); atomicAdd(pp + 1, ry);
        atomicAdd(pp + 2, rz); atomicAdd(pp + 3, rw);
    }
    red[t] = make_float4(sx, sy, sz, sw);
    __syncthreads();
    if (rh == 0) {
        float4 tot = red[c4];
        #pragma unroll
        for (int i = 1; i < 8; ++i) {
            float4 o = red[i * 32 + c4];
            tot.x += o.x; tot.y += o.y; tot.z += o.z; tot.w += o.w;
        }
        float* sp = &sums[c4 * 4];
        atomicAdd(sp + 0, tot.x); atomicAdd(sp + 1, tot.y);
        atomicAdd(sp + 2, tot.z); atomicAdd(sp + 3, tot.w);
    }
    __syncthreads();
    red[t] = make_float4(qx, qy, qz, qw);
    __syncthreads();
    if (rh == 0) {
        float4 tot = red[c4];
        #pragma unroll
        for (int i = 1; i < 8; ++i) {
            float4 o = red[i * 32 + c4];
            tot.x += o.x; tot.y += o.y; tot.z += o.z; tot.w += o.w;
        }
        float* sp = &sumsq[c4 * 4];
        atomicAdd(sp + 0, tot.x); atomicAdd(sp + 1, tot.y);
        atomicAdd(sp + 2, tot.z); atomicAdd(sp + 3, tot.w);
    }
}

// ---------------- W-fold only (critical path): blocks 0..63 fold W, block 64 folds fb ----------------
__global__ __launch_bounds__(256) void k_fold(const float* __restrict__ sums,
                                              const float* __restrict__ sumsq,
                                              const float* __restrict__ bng,
                                              const float* __restrict__ bnb,
                                              const float* __restrict__ Wnext,
                                              const float* __restrict__ fbnext,
                                              unsigned short* __restrict__ WLnext,
                                              float* __restrict__ Fbnext) {
    __shared__ float sA[HDIM], sB[HDIM];
    int t = threadIdx.x;
    if (t < HDIM) {
        float mu = sums[t] * (1.f / N_NODES);
        float var = fmaxf(sumsq[t] * (1.f / N_NODES) - mu * mu, 0.f);
        float inv = rsqrtf(var + BN_EPS);
        float a = bng[t] * inv;
        sA[t] = a;
        sB[t] = bnb[t] - a * mu;
    }
    __syncthreads();
    if (blockIdx.x < 64) {
        int idx = blockIdx.x * 256 + t;
        int k = idx >> 7, c = idx & 127;
        WLnext[wl_index(k, c)] = f2bf(sA[k] * Wnext[idx]);
    } else if (t < HDIM) {
        float a = fbnext[t];
        for (int k = 0; k < HDIM; ++k) a = fmaf(sB[k], Wnext[k * HDIM + t], a);
        Fbnext[t] = a;
    }
}

// ---------------- deferred pooled heads: one block per graph, all 3 layers ----------------
__global__ __launch_bounds__(256) void k_heads1(const float* __restrict__ statsAll,
                                                const int* __restrict__ gs,
                                                const float* __restrict__ bng0, const float* __restrict__ bnb0,
                                                const float* __restrict__ bng1, const float* __restrict__ bnb1,
                                                const float* __restrict__ bng2, const float* __restrict__ bnb2,
                                                const float* __restrict__ lw0, const float* __restrict__ lb0,
                                                const float* __restrict__ lw1, const float* __restrict__ lb1,
                                                const float* __restrict__ lw2, const float* __restrict__ lb2,
                                                float* __restrict__ pl_all) {
    __shared__ float sA3[3][HDIM], sB3[3][HDIM];
    __shared__ float red[8][HID];
    int g = blockIdx.x, t = threadIdx.x;
    const float* bngs[3] = {bng0, bng1, bng2};
    const float* bnbs[3] = {bnb0, bnb1, bnb2};
    const float* lws[3] = {lw0, lw1, lw2};
    const float* lbs[3] = {lb0, lb1, lb2};
    if (t < HDIM) {
        #pragma unroll
        for (int l = 0; l < 3; ++l) {
            const float* su = statsAll + (size_t)l * STATS_STRIDE;
            float mu = su[t] * (1.f / N_NODES);
            float var = fmaxf(su[128 + t] * (1.f / N_NODES) - mu * mu, 0.f);
            float inv = rsqrtf(var + BN_EPS);
            float a = bngs[l][t] * inv;
            sA3[l][t] = a;
            sB3[l][t] = bnbs[l][t] - a * mu;
        }
    }
    __syncthreads();
    float cnt = (float)(gs[g + 1] - gs[g]);
    int col = t & 31, kq = t >> 5;
    #pragma unroll
    for (int l = 0; l < 3; ++l) {
        const float* pg = statsAll + (size_t)l * STATS_STRIDE + 256 + (size_t)g * HDIM;
        float part = 0.f;
        #pragma unroll
        for (int kk = 0; kk < 16; ++kk) {
            int k = kq * 16 + kk;
            float pin = fmaf(sA3[l][k], pg[k], cnt * sB3[l][k]);
            part = fmaf(pin, lws[l][k * HID + col], part);
        }
        red[kq][col] = part;
        __syncthreads();
        if (kq == 0) {
            float s = red[0][col] + red[1][col] + red[2][col] + red[3][col]
                    + red[4][col] + red[5][col] + red[6][col] + red[7][col];
            pl_all[((size_t)l * G_GRAPHS + g) * HID + col] = fmaxf(s + lbs[l][col], 0.f);
        }
        __syncthreads();
    }
}

// ---------------- final: BN(pl) -> MLP -> BN -> relu -> logits -> log_softmax ----------------
__global__ __launch_bounds__(256) void k_final(const float* __restrict__ pl_all,
                                               const float* __restrict__ lg0, const float* __restrict__ lbt0,
                                               const float* __restrict__ lg1, const float* __restrict__ lbt1,
                                               const float* __restrict__ lg2, const float* __restrict__ lbt2,
                                               const float* __restrict__ mw1,
                                               const float* __restrict__ mg,
                                               const float* __restrict__ mb,
                                               const float* __restrict__ mw2,
                                               float* __restrict__ out) {
    __shared__ float pl3[3 * G_GRAPHS * HID];   // 24 KB
    __shared__ float w1[3 * HID * HID];         // 12 KB
    __shared__ float hm[G_GRAPHS][HID];         // 8 KB
    __shared__ float sc[96], sh[96];
    __shared__ float lgt[G_GRAPHS][NCLS];
    __shared__ float w2[HID * NCLS];
    int t = threadIdx.x;
    const float* lgs[3] = {lg0, lg1, lg2};
    const float* lbts[3] = {lbt0, lbt1, lbt2};
    for (int i = t; i < 3 * G_GRAPHS * HID; i += 256) pl3[i] = pl_all[i];
    for (int i = t; i < 3 * HID * HID; i += 256) w1[i] = mw1[i];
    for (int i = t; i < HID * NCLS; i += 256) w2[i] = mw2[i];
    __syncthreads();
    if (t < 96) {
        int l = t >> 5, c = t & 31;
        float s = 0.f, q = 0.f;
        for (int g = 0; g < G_GRAPHS; ++g) {
            float v = pl3[(l * G_GRAPHS + g) * HID + c];
            s += v; q = fmaf(v, v, q);
        }
        float mu = s * (1.f / G_GRAPHS);
        float var = fmaxf(q * (1.f / G_GRAPHS) - mu * mu, 0.f);
        float inv = rsqrtf(var + BN_EPS);
        float a = lgs[l][c] * inv;
        sc[t] = a;
        sh[t] = lbts[l][c] - a * mu;
    }
    __syncthreads();
    for (int i = t; i < 3 * G_GRAPHS * HID; i += 256) {
        int l = i / (G_GRAPHS * HID);
        int c = i & 31;
        pl3[i] = fmaf(pl3[i], sc[l * 32 + c], sh[l * 32 + c]);
    }
    __syncthreads();
    for (int i = t; i < G_GRAPHS * HID; i += 256) {
        int g = i >> 5, c = i & 31;
        float acc = 0.f;
        #pragma unroll
        for (int l = 0; l < 3; ++l)
            for (int k = 0; k < HID; ++k)
                acc = fmaf(pl3[(l * G_GRAPHS + g) * HID + k], w1[(l * HID + k) * HID + c], acc);
        hm[g][c] = acc;
    }
    __syncthreads();
    if (t < HID) {
        float s = 0.f, q = 0.f;
        for (int g = 0; g < G_GRAPHS; ++g) {
            float v = hm[g][t];
            s += v; q = fmaf(v, v, q);
        }
        float mu = s * (1.f / G_GRAPHS);
        float var = fmaxf(q * (1.f / G_GRAPHS) - mu * mu, 0.f);
        float inv = rsqrtf(var + BN_EPS);
        float a = mg[t] * inv;
        sc[t] = a;
        sh[t] = mb[t] - a * mu;
    }
    __syncthreads();
    for (int i = t; i < G_GRAPHS * HID; i += 256) {
        int g = i >> 5, c = i & 31;
        hm[g][c] = fmaxf(fmaf(hm[g][c], sc[c], sh[c]), 0.f);
    }
    __syncthreads();
    for (int i = t; i < G_GRAPHS * NCLS; i += 256) {
        int g = i / NCLS, c = i % NCLS;
        float acc = 0.f;
        for (int k = 0; k < HID; ++k) acc = fmaf(hm[g][k], w2[k * NCLS + c], acc);
        lgt[g][c] = acc;
    }
    __syncthreads();
    if (t < G_GRAPHS) {
        float mx = -INFINITY;
        for (int c = 0; c < NCLS; ++c) mx = fmaxf(mx, lgt[t][c]);
        float s = 0.f;
        for (int c = 0; c < NCLS; ++c) s += expf(lgt[t][c] - mx);
        float lse = mx + logf(s);
        for (int c = 0; c < NCLS; ++c) out[t * NCLS + c] = lgt[t][c] - lse;
    }
}

extern "C" void kernel_launch(void* const* d_in, const int* in_sizes, int n_in,
                              void* d_out, int out_size, void* d_ws, size_t ws_size,
                              hipStream_t stream) {
    (void)in_sizes; (void)n_in; (void)out_size; (void)ws_size;
    const float* feat = (const float*)d_in[0];
    const int* src = (const int*)d_in[1];
    const int* dst = (const int*)d_in[2];
    const int* seg = (const int*)d_in[3];
    auto LP = [&](int l, int j) { return (const float*)d_in[4 + 10 * l + j]; };
    const float* mw1 = (const float*)d_in[34];
    const float* mg  = (const float*)d_in[35];
    const float* mb  = (const float*)d_in[36];
    const float* mw2 = (const float*)d_in[37];

    char* p = (char*)d_ws;
    auto alloc = [&](size_t bytes) { char* r = p; p += (bytes + 255) & ~(size_t)255; return r; };
    unsigned short* Hb = (unsigned short*)alloc((size_t)N_NODES * HDIM * 2);
    unsigned short* Yb = (unsigned short*)alloc((size_t)N_NODES * HDIM * 2);
    int*   ssrc   = (int*)alloc((size_t)N_EDGES * 4);
    unsigned int* gbuf = (unsigned int*)alloc((size_t)N_EDGES * 4);
    int*   rp     = (int*)alloc((size_t)(N_NODES + 1) * 4);
    int*   bcnt   = (int*)alloc((size_t)NBUCK * 4);       // zeroed (adjacent to statsAll)
    float* statsAll = (float*)alloc((size_t)3 * STATS_STRIDE * 4);
    int*   bbase  = (int*)alloc((size_t)(NBUCK + 1) * 4);
    int*   bcur   = (int*)alloc((size_t)NBUCK * 4);
    float* pl_all = (float*)alloc((size_t)3 * G_GRAPHS * HID * 4);
    int*   gs     = (int*)alloc((size_t)(G_GRAPHS + 1) * 4);
    unsigned short* WL = (unsigned short*)alloc((size_t)3 * HDIM * HDIM * 2);
    float* Fb     = (float*)alloc((size_t)3 * HDIM * 4);

    // zero bcnt + all per-layer stats (adjacent in ws)
    size_t zspan = (size_t)((char*)(statsAll + 3 * STATS_STRIDE) - (char*)bcnt);
    hipMemsetAsync(bcnt, 0, zspan, stream);

    // layer-0 W prep FIRST (k_mega0's gemm blocks read WL)
    k_prep_w<<<16, 256, 0, stream>>>(LP(0, 0), WL);
    // bucket histogram + layer-0 GEMM, fused (independent inputs)
    k_mega0<<<NCHUNK + NGB_GEMM, 256, 0, stream>>>(dst, bcnt, WL, feat, LP(0, 1), Hb);
    k_bscan<<<1, 256, 0, stream>>>(bcnt, bbase, bcur, seg, gs);
    k_bscatter<<<NCHUNK, 256, 0, stream>>>(dst, src, bcur, gbuf);
    k_bsort<<<NBUCK, 256, CAP_OUT * 4, stream>>>(bbase, gbuf, ssrc, rp);

    for (int l = 0; l < 3; ++l) {
        float* sums   = statsAll + (size_t)l * STATS_STRIDE;
        float* sumsq  = sums + 128;
        float* pooled = sums + 256;
        if (l > 0) {
            k_gemm_mfma<false><<<NGB_GEMM, 256, 0, stream>>>(
                Yb, WL + (size_t)l * HDIM * HDIM, Fb + (size_t)l * HDIM, Hb);
        }
        k_edge<<<(N_NODES + 3) / 4, 256, 0, stream>>>(Hb, rp, ssrc, LP(l, 2), LP(l, 3), Yb);
        k_stats_pool<<<NB_SCAN, 256, 0, stream>>>(Yb, seg, sums, sumsq, pooled);
        if (l < 2) {
            k_fold<<<65, 256, 0, stream>>>(sums, sumsq, LP(l, 4), LP(l, 5),
                                           LP(l + 1, 0), LP(l + 1, 1),
                                           WL + (size_t)(l + 1) * HDIM * HDIM,
                                           Fb + (size_t)(l + 1) * HDIM);
        }
    }
    // deferred heads (off the per-layer critical path)
    k_heads1<<<G_GRAPHS, 256, 0, stream>>>(statsAll, gs,
                                           LP(0, 4), LP(0, 5), LP(1, 4), LP(1, 5), LP(2, 4), LP(2, 5),
                                           LP(0, 6), LP(0, 7), LP(1, 6), LP(1, 7), LP(2, 6), LP(2, 7),
                                           pl_all);
    k_final<<<1, 256, 0, stream>>>(pl_all,
                                   LP(0, 8), LP(0, 9), LP(1, 8), LP(1, 9), LP(2, 8), LP(2, 9),
                                   mw1, mg, mb, mw2, (float*)d_out);
}